// Round 1
// baseline (1585.975 us; speedup 1.0000x reference)
//
#include <hip/hip_runtime.h>
#include <cfloat>
#include <cmath>

constexpr int B = 4;
constexpr int L = 4096;
constexpr int D = 512;
constexpr int NH = 8;
constexpr int DH = 64;
constexpr int KN = 16;
constexpr int M = B * L;          // 16384 rows
constexpr int N_IN = 3 * D;       // 1536

// ---------------------------------------------------------------------------
// Kernel 1: top-16 nearest neighbors per query (per batch), + is_in flag.
// One thread = one query; positions for the whole batch staged in LDS.
// ---------------------------------------------------------------------------
__global__ __launch_bounds__(64) void topk_kernel(const float* __restrict__ pos,
                                                  int* __restrict__ nbr,
                                                  int* __restrict__ isin) {
  __shared__ float sx[L], sy[L], sz[L];
  const int b = blockIdx.x >> 6;       // 64 blocks per batch (L/64)
  const int lblk = blockIdx.x & 63;
  const float* p = pos + (size_t)b * L * 3;
  for (int i = threadIdx.x; i < L; i += 64) {
    sx[i] = p[i * 3 + 0];
    sy[i] = p[i * 3 + 1];
    sz[i] = p[i * 3 + 2];
  }
  __syncthreads();

  const int l = lblk * 64 + threadIdx.x;
  const float qx = sx[l], qy = sy[l], qz = sz[l];

  float d[KN];
  int id[KN];
#pragma unroll
  for (int t = 0; t < KN; ++t) { d[t] = FLT_MAX; id[t] = -1; }

#pragma unroll 4
  for (int j = 0; j < L; ++j) {
    const float dx = qx - sx[j];
    const float dy = qy - sy[j];
    const float dz = qz - sz[j];
    const float dist = sqrtf(dx * dx + dy * dy + dz * dz);
    if (dist < d[KN - 1]) {
      // static-index insertion into sorted top-K (strict < => stable ties,
      // lower index wins, matching lax.top_k)
      float cd = dist; int ci = j;
#pragma unroll
      for (int t = 0; t < KN; ++t) {
        const bool lt = cd < d[t];
        const float nd = lt ? cd : d[t];
        const int   ni = lt ? ci : id[t];
        const float xd = lt ? d[t] : cd;
        const int   xi = lt ? id[t] : ci;
        d[t] = nd; id[t] = ni; cd = xd; ci = xi;
      }
    }
  }

  int* onb = nbr + (size_t)(b * L + l) * KN;
  int any = 0;
#pragma unroll
  for (int t = 0; t < KN; ++t) {
    onb[t] = id[t];
    any |= (id[t] == l) ? 1 : 0;
  }
  isin[b * L + l] = any;
}

// ---------------------------------------------------------------------------
// Kernel 2: fp32 GEMM  C[m,n] = A[m,:] . W[n,:] + bias[n]   (A: MxD, W: NtotxD)
// mode 0: in_proj -> scale cols < D by 0.125 (q scale), write to C (stride Ntot)
// mode 1: out_proj -> epilogue select: out = isin[row] ? val : X[row, col]
// Tile 128x128xBK16, 256 threads, 8x8 per thread.
// ---------------------------------------------------------------------------
constexpr int BM = 128, BN = 128, BK = 16;

__global__ __launch_bounds__(256) void gemm_kernel(const float* __restrict__ A,
                                                   const float* __restrict__ W,
                                                   const float* __restrict__ bias,
                                                   float* __restrict__ C,
                                                   int Ntot, int mode,
                                                   const float* __restrict__ X,
                                                   const int* __restrict__ isin) {
  __shared__ float As[BK][BM + 4];
  __shared__ float Bs[BK][BN + 4];
  const int tid = threadIdx.x;
  const int m0 = blockIdx.x * BM;
  const int n0 = blockIdx.y * BN;
  const int tm = tid >> 4;   // 0..15
  const int tn = tid & 15;   // 0..15

  float acc[8][8];
#pragma unroll
  for (int i = 0; i < 8; ++i)
#pragma unroll
    for (int j = 0; j < 8; ++j) acc[i][j] = 0.f;

  for (int k0 = 0; k0 < D; k0 += BK) {
#pragma unroll
    for (int i = 0; i < 2; ++i) {
      const int t = tid + i * 256;       // 0..511
      const int r = t >> 2;              // 0..127
      const int kc = (t & 3) * 4;        // 0,4,8,12
      const float4 a = *reinterpret_cast<const float4*>(&A[(size_t)(m0 + r) * D + k0 + kc]);
      As[kc + 0][r] = a.x; As[kc + 1][r] = a.y; As[kc + 2][r] = a.z; As[kc + 3][r] = a.w;
      const float4 w = *reinterpret_cast<const float4*>(&W[(size_t)(n0 + r) * D + k0 + kc]);
      Bs[kc + 0][r] = w.x; Bs[kc + 1][r] = w.y; Bs[kc + 2][r] = w.z; Bs[kc + 3][r] = w.w;
    }
    __syncthreads();
#pragma unroll
    for (int k = 0; k < BK; ++k) {
      float a_[8], b_[8];
      *reinterpret_cast<float4*>(&a_[0]) = *reinterpret_cast<const float4*>(&As[k][tm * 8]);
      *reinterpret_cast<float4*>(&a_[4]) = *reinterpret_cast<const float4*>(&As[k][tm * 8 + 4]);
      *reinterpret_cast<float4*>(&b_[0]) = *reinterpret_cast<const float4*>(&Bs[k][tn * 8]);
      *reinterpret_cast<float4*>(&b_[4]) = *reinterpret_cast<const float4*>(&Bs[k][tn * 8 + 4]);
#pragma unroll
      for (int i = 0; i < 8; ++i)
#pragma unroll
        for (int j = 0; j < 8; ++j) acc[i][j] = fmaf(a_[i], b_[j], acc[i][j]);
    }
    __syncthreads();
  }

  const float scl = (mode == 0 && n0 < D) ? 0.125f : 1.0f;  // q scale = 1/sqrt(64)
#pragma unroll
  for (int i = 0; i < 8; ++i) {
    const int row = m0 + tm * 8 + i;
    const int isrow = (mode == 1) ? isin[row] : 1;
#pragma unroll
    for (int jj = 0; jj < 2; ++jj) {
      float4 v;
      float* vp = &v.x;
#pragma unroll
      for (int j = 0; j < 4; ++j) {
        const int col = n0 + tn * 8 + jj * 4 + j;
        float val = (acc[i][jj * 4 + j] + bias[col]) * scl;
        if (mode == 1 && !isrow) val = X[(size_t)row * D + col];
        vp[j] = val;
      }
      *reinterpret_cast<float4*>(&C[(size_t)row * Ntot + n0 + tn * 8 + jj * 4]) = v;
    }
  }
}

// ---------------------------------------------------------------------------
// Kernel 3: gathered 16-neighbor attention. One wave per (b,l); 4 waves/block.
// Lane layout phase 1: h = lane>>3, neighbors {lane&7, (lane&7)+8} -> scores.
// Phase 2: per-head softmax (via LDS), lane computes 8 ctx dims.
// ---------------------------------------------------------------------------
__global__ __launch_bounds__(256) void attn_kernel(const float* __restrict__ qkv,
                                                   const int* __restrict__ nbr,
                                                   float* __restrict__ ctx) {
  __shared__ float sc[4][NH][KN];
  const int wave = threadIdx.x >> 6;
  const int lane = threadIdx.x & 63;
  const int bl = blockIdx.x * 4 + wave;        // 0..16383
  const int bbase = (bl >> 12) << 12;          // b * L
  const int* nb = nbr + (size_t)bl * KN;

  const int h = lane >> 3;
  const int n0 = lane & 7;

  // load q segment for this head into registers
  const float* q = qkv + (size_t)bl * N_IN + h * DH;
  float4 qr[16];
#pragma unroll
  for (int i = 0; i < 16; ++i)
    qr[i] = *reinterpret_cast<const float4*>(&q[i * 4]);

  // phase 1: scores for 2 neighbors
#pragma unroll
  for (int t = 0; t < 2; ++t) {
    const int n = n0 + t * 8;
    const int j = nb[n];
    const float* kr = qkv + (size_t)(bbase + j) * N_IN + D + h * DH;
    float a0 = 0.f, a1 = 0.f;
#pragma unroll
    for (int i = 0; i < 16; i += 2) {
      const float4 k0 = *reinterpret_cast<const float4*>(&kr[i * 4]);
      const float4 k1 = *reinterpret_cast<const float4*>(&kr[i * 4 + 4]);
      a0 = fmaf(qr[i].x, k0.x, a0); a0 = fmaf(qr[i].y, k0.y, a0);
      a0 = fmaf(qr[i].z, k0.z, a0); a0 = fmaf(qr[i].w, k0.w, a0);
      a1 = fmaf(qr[i + 1].x, k1.x, a1); a1 = fmaf(qr[i + 1].y, k1.y, a1);
      a1 = fmaf(qr[i + 1].z, k1.z, a1); a1 = fmaf(qr[i + 1].w, k1.w, a1);
    }
    sc[wave][h][n] = a0 + a1;
  }
  __syncthreads();

  // phase 2: softmax over 16 for this lane's head
  float e[KN];
  float mx = -FLT_MAX;
#pragma unroll
  for (int n = 0; n < KN; ++n) mx = fmaxf(mx, sc[wave][h][n]);
  float sum = 0.f;
#pragma unroll
  for (int n = 0; n < KN; ++n) { e[n] = expf(sc[wave][h][n] - mx); sum += e[n]; }
  const float inv = 1.0f / sum;

  const int d0 = (lane & 7) * 8;
  float acc[8];
#pragma unroll
  for (int i = 0; i < 8; ++i) acc[i] = 0.f;
#pragma unroll
  for (int n = 0; n < KN; ++n) {
    const int j = nb[n];
    const float* vr = qkv + (size_t)(bbase + j) * N_IN + 2 * D + h * DH + d0;
    const float w = e[n] * inv;
    const float4 v0 = *reinterpret_cast<const float4*>(&vr[0]);
    const float4 v1 = *reinterpret_cast<const float4*>(&vr[4]);
    acc[0] = fmaf(w, v0.x, acc[0]); acc[1] = fmaf(w, v0.y, acc[1]);
    acc[2] = fmaf(w, v0.z, acc[2]); acc[3] = fmaf(w, v0.w, acc[3]);
    acc[4] = fmaf(w, v1.x, acc[4]); acc[5] = fmaf(w, v1.y, acc[5]);
    acc[6] = fmaf(w, v1.z, acc[6]); acc[7] = fmaf(w, v1.w, acc[7]);
  }
  float* cp = ctx + (size_t)bl * D + h * DH + d0;
  *reinterpret_cast<float4*>(&cp[0]) = make_float4(acc[0], acc[1], acc[2], acc[3]);
  *reinterpret_cast<float4*>(&cp[4]) = make_float4(acc[4], acc[5], acc[6], acc[7]);
}

// ---------------------------------------------------------------------------
extern "C" void kernel_launch(void* const* d_in, const int* in_sizes, int n_in,
                              void* d_out, int out_size, void* d_ws, size_t ws_size,
                              hipStream_t stream) {
  const float* x     = (const float*)d_in[0];
  const float* pos   = (const float*)d_in[1];
  const float* in_w  = (const float*)d_in[2];
  const float* in_b  = (const float*)d_in[3];
  const float* out_w = (const float*)d_in[4];
  const float* out_b = (const float*)d_in[5];
  float* out = (float*)d_out;

  // workspace layout
  const size_t nbr_bytes  = (size_t)M * KN * sizeof(int);      // 1 MB
  const size_t isin_bytes = (size_t)M * sizeof(int);           // 64 KB
  const size_t qkv_bytes  = (size_t)M * N_IN * sizeof(float);  // 100.7 MB
  const size_t ctx_bytes  = (size_t)M * D * sizeof(float);     // 33.5 MB
  const size_t need = nbr_bytes + isin_bytes + qkv_bytes + ctx_bytes + 1024;
  if (ws_size < need) return;  // fail loudly (validation will catch it)

  char* w = (char*)d_ws;
  int*   nbr  = (int*)w;                 w += (nbr_bytes + 255) & ~(size_t)255;
  int*   isin = (int*)w;                 w += (isin_bytes + 255) & ~(size_t)255;
  float* qkv  = (float*)w;               w += (qkv_bytes + 255) & ~(size_t)255;
  float* ctx  = (float*)w;

  // 1) top-k neighbors
  topk_kernel<<<B * (L / 64), 64, 0, stream>>>(pos, nbr, isin);

  // 2) in_proj: qkv = x @ in_w^T + in_b  (q cols scaled by 0.125)
  gemm_kernel<<<dim3(M / BM, N_IN / BN), 256, 0, stream>>>(
      x, in_w, in_b, qkv, N_IN, 0, nullptr, nullptr);

  // 3) gathered neighbor attention -> ctx
  attn_kernel<<<M / 4, 256, 0, stream>>>(qkv, nbr, ctx);

  // 4) out_proj + is_in select
  gemm_kernel<<<dim3(M / BM, D / BN), 256, 0, stream>>>(
      ctx, out_w, out_b, out, D, 1, x, isin);
}

// Round 2
// 717.656 us; speedup vs baseline: 2.2099x; 2.2099x over previous
//
#include <hip/hip_runtime.h>
#include <cfloat>
#include <cmath>

constexpr int B = 4;
constexpr int L = 4096;
constexpr int D = 512;
constexpr int NH = 8;
constexpr int DH = 64;
constexpr int KN = 16;
constexpr int M = B * L;          // 16384 rows
constexpr int N_IN = 3 * D;       // 1536

// ---------------------------------------------------------------------------
// Kernel 1: top-16 nearest neighbors, one WAVE per query. 4 waves/block.
// Each lane owns 64 candidates (c = j*64 + lane), keeps a branchless sorted
// top-8 in registers (static indices only), then 16 rounds of wave-wide u64
// argmin on packed (dist_bits<<32 | index) extract the global top-16 with
// exact lax.top_k tie semantics (lower index wins on equal distance).
// ---------------------------------------------------------------------------
__global__ __launch_bounds__(256) void topk_kernel(const float* __restrict__ pos,
                                                   int* __restrict__ nbr,
                                                   int* __restrict__ isin) {
  __shared__ float sx[L], sy[L], sz[L];   // 48 KB
  const int wave = threadIdx.x >> 6;
  const int lane = threadIdx.x & 63;
  const int b = blockIdx.x >> 10;         // 1024 blocks per batch
  const int blk = blockIdx.x & 1023;
  const int l = blk * 4 + wave;           // this wave's query
  const int row = b * L + l;

  const float* p = pos + (size_t)b * L * 3;
  for (int i = threadIdx.x; i < L; i += 256) {
    sx[i] = p[3 * i + 0];
    sy[i] = p[3 * i + 1];
    sz[i] = p[3 * i + 2];
  }
  __syncthreads();

  const float qx = sx[l], qy = sy[l], qz = sz[l];

  // per-lane sorted top-8 (ascending), branchless static-index insertion
  float d0 = FLT_MAX, d1 = FLT_MAX, d2 = FLT_MAX, d3 = FLT_MAX;
  float d4 = FLT_MAX, d5 = FLT_MAX, d6 = FLT_MAX, d7 = FLT_MAX;
  int i0 = 0x7fffffff, i1 = 0x7fffffff, i2 = 0x7fffffff, i3 = 0x7fffffff;
  int i4 = 0x7fffffff, i5 = 0x7fffffff, i6 = 0x7fffffff, i7 = 0x7fffffff;

#pragma unroll 4
  for (int j = 0; j < 64; ++j) {
    const int c = j * 64 + lane;          // lanes stride-1 in LDS: conflict-free
    const float dx = qx - sx[c];
    const float dy = qy - sy[c];
    const float dz = qz - sz[c];
    float cd = sqrtf(fmaf(dx, dx, fmaf(dy, dy, dz * dz)));
    int ci = c;
    // 8-level insert: strict < keeps earlier (lower) index first on ties
#define INS(dd, ii)                                        \
    {                                                      \
      const bool lt = cd < dd;                             \
      const float nd = lt ? cd : dd;                       \
      const int ni = lt ? ci : ii;                         \
      const float xd = lt ? dd : cd;                       \
      const int xi = lt ? ii : ci;                         \
      dd = nd; ii = ni; cd = xd; ci = xi;                  \
    }
    INS(d0, i0) INS(d1, i1) INS(d2, i2) INS(d3, i3)
    INS(d4, i4) INS(d5, i5) INS(d6, i6) INS(d7, i7)
#undef INS
  }

  // 16 extraction rounds: global min of packed (dist_bits, index)
  int res[KN];
  int any = 0;
#pragma unroll
  for (int r = 0; r < KN; ++r) {
    unsigned long long pk =
        ((unsigned long long)__float_as_uint(d0) << 32) | (unsigned)i0;
#pragma unroll
    for (int s = 1; s < 64; s <<= 1) {
      const unsigned long long o = __shfl_xor(pk, s, 64);
      pk = (o < pk) ? o : pk;
    }
    const int widx = (int)(unsigned)(pk & 0xffffffffull);
    res[r] = widx;
    any |= (widx == l) ? 1 : 0;
    // winner lane shifts its sorted list down (predicated, static indices)
    const bool win = (i0 == widx);
    d0 = win ? d1 : d0; i0 = win ? i1 : i0;
    d1 = win ? d2 : d1; i1 = win ? i2 : i1;
    d2 = win ? d3 : d2; i2 = win ? i3 : i2;
    d3 = win ? d4 : d3; i3 = win ? i4 : i3;
    d4 = win ? d5 : d4; i4 = win ? i5 : i4;
    d5 = win ? d6 : d5; i5 = win ? i6 : i5;
    d6 = win ? d7 : d6; i6 = win ? i7 : i6;
    d7 = win ? FLT_MAX : d7; i7 = win ? 0x7fffffff : i7;
  }

  if (lane == 0) {
    int* onb = nbr + (size_t)row * KN;
    int4* o4 = reinterpret_cast<int4*>(onb);
    o4[0] = make_int4(res[0], res[1], res[2], res[3]);
    o4[1] = make_int4(res[4], res[5], res[6], res[7]);
    o4[2] = make_int4(res[8], res[9], res[10], res[11]);
    o4[3] = make_int4(res[12], res[13], res[14], res[15]);
    isin[row] = any;
  }
}

// ---------------------------------------------------------------------------
// Kernel 2: fp32 GEMM  C[m,n] = A[m,:] . W[n,:] + bias[n]   (A: MxD, W: NtotxD)
// mode 0: in_proj -> scale cols < D by 0.125 (q scale), write to C (stride Ntot)
// mode 1: out_proj -> epilogue select: out = isin[row] ? val : X[row, col]
// Tile 128x128xBK16, 256 threads, 8x8 per thread.
// ---------------------------------------------------------------------------
constexpr int BM = 128, BN = 128, BK = 16;

__global__ __launch_bounds__(256) void gemm_kernel(const float* __restrict__ A,
                                                   const float* __restrict__ W,
                                                   const float* __restrict__ bias,
                                                   float* __restrict__ C,
                                                   int Ntot, int mode,
                                                   const float* __restrict__ X,
                                                   const int* __restrict__ isin) {
  __shared__ float As[BK][BM + 4];
  __shared__ float Bs[BK][BN + 4];
  const int tid = threadIdx.x;
  const int m0 = blockIdx.x * BM;
  const int n0 = blockIdx.y * BN;
  const int tm = tid >> 4;   // 0..15
  const int tn = tid & 15;   // 0..15

  float acc[8][8];
#pragma unroll
  for (int i = 0; i < 8; ++i)
#pragma unroll
    for (int j = 0; j < 8; ++j) acc[i][j] = 0.f;

  for (int k0 = 0; k0 < D; k0 += BK) {
#pragma unroll
    for (int i = 0; i < 2; ++i) {
      const int t = tid + i * 256;       // 0..511
      const int r = t >> 2;              // 0..127
      const int kc = (t & 3) * 4;        // 0,4,8,12
      const float4 a = *reinterpret_cast<const float4*>(&A[(size_t)(m0 + r) * D + k0 + kc]);
      As[kc + 0][r] = a.x; As[kc + 1][r] = a.y; As[kc + 2][r] = a.z; As[kc + 3][r] = a.w;
      const float4 w = *reinterpret_cast<const float4*>(&W[(size_t)(n0 + r) * D + k0 + kc]);
      Bs[kc + 0][r] = w.x; Bs[kc + 1][r] = w.y; Bs[kc + 2][r] = w.z; Bs[kc + 3][r] = w.w;
    }
    __syncthreads();
#pragma unroll
    for (int k = 0; k < BK; ++k) {
      float a_[8], b_[8];
      *reinterpret_cast<float4*>(&a_[0]) = *reinterpret_cast<const float4*>(&As[k][tm * 8]);
      *reinterpret_cast<float4*>(&a_[4]) = *reinterpret_cast<const float4*>(&As[k][tm * 8 + 4]);
      *reinterpret_cast<float4*>(&b_[0]) = *reinterpret_cast<const float4*>(&Bs[k][tn * 8]);
      *reinterpret_cast<float4*>(&b_[4]) = *reinterpret_cast<const float4*>(&Bs[k][tn * 8 + 4]);
#pragma unroll
      for (int i = 0; i < 8; ++i)
#pragma unroll
        for (int j = 0; j < 8; ++j) acc[i][j] = fmaf(a_[i], b_[j], acc[i][j]);
    }
    __syncthreads();
  }

  const float scl = (mode == 0 && n0 < D) ? 0.125f : 1.0f;  // q scale = 1/sqrt(64)
#pragma unroll
  for (int i = 0; i < 8; ++i) {
    const int row = m0 + tm * 8 + i;
    const int isrow = (mode == 1) ? isin[row] : 1;
#pragma unroll
    for (int jj = 0; jj < 2; ++jj) {
      float4 v;
      float* vp = &v.x;
#pragma unroll
      for (int j = 0; j < 4; ++j) {
        const int col = n0 + tn * 8 + jj * 4 + j;
        float val = (acc[i][jj * 4 + j] + bias[col]) * scl;
        if (mode == 1 && !isrow) val = X[(size_t)row * D + col];
        vp[j] = val;
      }
      *reinterpret_cast<float4*>(&C[(size_t)row * Ntot + n0 + tn * 8 + jj * 4]) = v;
    }
  }
}

// ---------------------------------------------------------------------------
// Kernel 3: gathered 16-neighbor attention. One wave per (b,l); 4 waves/block.
// ---------------------------------------------------------------------------
__global__ __launch_bounds__(256) void attn_kernel(const float* __restrict__ qkv,
                                                   const int* __restrict__ nbr,
                                                   float* __restrict__ ctx) {
  __shared__ float sc[4][NH][KN];
  const int wave = threadIdx.x >> 6;
  const int lane = threadIdx.x & 63;
  const int bl = blockIdx.x * 4 + wave;        // 0..16383
  const int bbase = (bl >> 12) << 12;          // b * L
  const int* nb = nbr + (size_t)bl * KN;

  const int h = lane >> 3;
  const int n0 = lane & 7;

  // load q segment for this head into registers
  const float* q = qkv + (size_t)bl * N_IN + h * DH;
  float4 qr[16];
#pragma unroll
  for (int i = 0; i < 16; ++i)
    qr[i] = *reinterpret_cast<const float4*>(&q[i * 4]);

  // phase 1: scores for 2 neighbors
#pragma unroll
  for (int t = 0; t < 2; ++t) {
    const int n = n0 + t * 8;
    const int j = nb[n];
    const float* kr = qkv + (size_t)(bbase + j) * N_IN + D + h * DH;
    float a0 = 0.f, a1 = 0.f;
#pragma unroll
    for (int i = 0; i < 16; i += 2) {
      const float4 k0 = *reinterpret_cast<const float4*>(&kr[i * 4]);
      const float4 k1 = *reinterpret_cast<const float4*>(&kr[i * 4 + 4]);
      a0 = fmaf(qr[i].x, k0.x, a0); a0 = fmaf(qr[i].y, k0.y, a0);
      a0 = fmaf(qr[i].z, k0.z, a0); a0 = fmaf(qr[i].w, k0.w, a0);
      a1 = fmaf(qr[i + 1].x, k1.x, a1); a1 = fmaf(qr[i + 1].y, k1.y, a1);
      a1 = fmaf(qr[i + 1].z, k1.z, a1); a1 = fmaf(qr[i + 1].w, k1.w, a1);
    }
    sc[wave][h][n] = a0 + a1;
  }
  __syncthreads();

  // phase 2: softmax over 16 for this lane's head
  float e[KN];
  float mx = -FLT_MAX;
#pragma unroll
  for (int n = 0; n < KN; ++n) mx = fmaxf(mx, sc[wave][h][n]);
  float sum = 0.f;
#pragma unroll
  for (int n = 0; n < KN; ++n) { e[n] = expf(sc[wave][h][n] - mx); sum += e[n]; }
  const float inv = 1.0f / sum;

  const int d0 = (lane & 7) * 8;
  float acc[8];
#pragma unroll
  for (int i = 0; i < 8; ++i) acc[i] = 0.f;
#pragma unroll
  for (int n = 0; n < KN; ++n) {
    const int j = nb[n];
    const float* vr = qkv + (size_t)(bbase + j) * N_IN + 2 * D + h * DH + d0;
    const float w = e[n] * inv;
    const float4 v0 = *reinterpret_cast<const float4*>(&vr[0]);
    const float4 v1 = *reinterpret_cast<const float4*>(&vr[4]);
    acc[0] = fmaf(w, v0.x, acc[0]); acc[1] = fmaf(w, v0.y, acc[1]);
    acc[2] = fmaf(w, v0.z, acc[2]); acc[3] = fmaf(w, v0.w, acc[3]);
    acc[4] = fmaf(w, v1.x, acc[4]); acc[5] = fmaf(w, v1.y, acc[5]);
    acc[6] = fmaf(w, v1.z, acc[6]); acc[7] = fmaf(w, v1.w, acc[7]);
  }
  float* cp = ctx + (size_t)bl * D + h * DH + d0;
  *reinterpret_cast<float4*>(&cp[0]) = make_float4(acc[0], acc[1], acc[2], acc[3]);
  *reinterpret_cast<float4*>(&cp[4]) = make_float4(acc[4], acc[5], acc[6], acc[7]);
}

// ---------------------------------------------------------------------------
extern "C" void kernel_launch(void* const* d_in, const int* in_sizes, int n_in,
                              void* d_out, int out_size, void* d_ws, size_t ws_size,
                              hipStream_t stream) {
  const float* x     = (const float*)d_in[0];
  const float* pos   = (const float*)d_in[1];
  const float* in_w  = (const float*)d_in[2];
  const float* in_b  = (const float*)d_in[3];
  const float* out_w = (const float*)d_in[4];
  const float* out_b = (const float*)d_in[5];
  float* out = (float*)d_out;

  // workspace layout
  const size_t nbr_bytes  = (size_t)M * KN * sizeof(int);      // 1 MB
  const size_t isin_bytes = (size_t)M * sizeof(int);           // 64 KB
  const size_t qkv_bytes  = (size_t)M * N_IN * sizeof(float);  // 100.7 MB
  const size_t ctx_bytes  = (size_t)M * D * sizeof(float);     // 33.5 MB
  const size_t need = nbr_bytes + isin_bytes + qkv_bytes + ctx_bytes + 1024;
  if (ws_size < need) return;  // fail loudly (validation will catch it)

  char* w = (char*)d_ws;
  int*   nbr  = (int*)w;                 w += (nbr_bytes + 255) & ~(size_t)255;
  int*   isin = (int*)w;                 w += (isin_bytes + 255) & ~(size_t)255;
  float* qkv  = (float*)w;               w += (qkv_bytes + 255) & ~(size_t)255;
  float* ctx  = (float*)w;

  // 1) top-k neighbors: one wave per query, 4 waves/block
  topk_kernel<<<B * (L / 4), 256, 0, stream>>>(pos, nbr, isin);

  // 2) in_proj: qkv = x @ in_w^T + in_b  (q cols scaled by 0.125)
  gemm_kernel<<<dim3(M / BM, N_IN / BN), 256, 0, stream>>>(
      x, in_w, in_b, qkv, N_IN, 0, nullptr, nullptr);

  // 3) gathered neighbor attention -> ctx
  attn_kernel<<<M / 4, 256, 0, stream>>>(qkv, nbr, ctx);

  // 4) out_proj + is_in select
  gemm_kernel<<<dim3(M / BM, D / BN), 256, 0, stream>>>(
      ctx, out_w, out_b, out, D, 1, x, isin);
}

// Round 3
// 448.698 us; speedup vs baseline: 3.5346x; 1.5994x over previous
//
#include <hip/hip_runtime.h>
#include <cfloat>
#include <cmath>

constexpr int B = 4;
constexpr int L = 4096;
constexpr int D = 512;
constexpr int NH = 8;
constexpr int DH = 64;
constexpr int KN = 16;
constexpr int M = B * L;          // 16384 rows
constexpr int N_IN = 3 * D;       // 1536

typedef __attribute__((ext_vector_type(8))) short short8;   // 8 bf16 = 4 VGPR
typedef __attribute__((ext_vector_type(4))) float f32x4;    // MFMA acc

__device__ __forceinline__ unsigned short f2bf(float f) {   // RN-even bf16
  unsigned u = __float_as_uint(f);
  u = u + 0x7fffu + ((u >> 16) & 1u);
  return (unsigned short)(u >> 16);
}
__device__ __forceinline__ float bf2f(unsigned short h) {
  return __uint_as_float(((unsigned)h) << 16);
}

// ---------------------------------------------------------------------------
// Kernel 1: top-16 nearest neighbors, one WAVE per query (unchanged, R2).
// ---------------------------------------------------------------------------
__global__ __launch_bounds__(256) void topk_kernel(const float* __restrict__ pos,
                                                   int* __restrict__ nbr,
                                                   int* __restrict__ isin) {
  __shared__ float sx[L], sy[L], sz[L];   // 48 KB
  const int wave = threadIdx.x >> 6;
  const int lane = threadIdx.x & 63;
  const int b = blockIdx.x >> 10;
  const int blk = blockIdx.x & 1023;
  const int l = blk * 4 + wave;
  const int row = b * L + l;

  const float* p = pos + (size_t)b * L * 3;
  for (int i = threadIdx.x; i < L; i += 256) {
    sx[i] = p[3 * i + 0];
    sy[i] = p[3 * i + 1];
    sz[i] = p[3 * i + 2];
  }
  __syncthreads();

  const float qx = sx[l], qy = sy[l], qz = sz[l];

  float d0 = FLT_MAX, d1 = FLT_MAX, d2 = FLT_MAX, d3 = FLT_MAX;
  float d4 = FLT_MAX, d5 = FLT_MAX, d6 = FLT_MAX, d7 = FLT_MAX;
  int i0 = 0x7fffffff, i1 = 0x7fffffff, i2 = 0x7fffffff, i3 = 0x7fffffff;
  int i4 = 0x7fffffff, i5 = 0x7fffffff, i6 = 0x7fffffff, i7 = 0x7fffffff;

#pragma unroll 4
  for (int j = 0; j < 64; ++j) {
    const int c = j * 64 + lane;
    const float dx = qx - sx[c];
    const float dy = qy - sy[c];
    const float dz = qz - sz[c];
    float cd = sqrtf(fmaf(dx, dx, fmaf(dy, dy, dz * dz)));
    int ci = c;
#define INS(dd, ii)                                        \
    {                                                      \
      const bool lt = cd < dd;                             \
      const float nd = lt ? cd : dd;                       \
      const int ni = lt ? ci : ii;                         \
      const float xd = lt ? dd : cd;                       \
      const int xi = lt ? ii : ci;                         \
      dd = nd; ii = ni; cd = xd; ci = xi;                  \
    }
    INS(d0, i0) INS(d1, i1) INS(d2, i2) INS(d3, i3)
    INS(d4, i4) INS(d5, i5) INS(d6, i6) INS(d7, i7)
#undef INS
  }

  int res[KN];
  int any = 0;
#pragma unroll
  for (int r = 0; r < KN; ++r) {
    unsigned long long pk =
        ((unsigned long long)__float_as_uint(d0) << 32) | (unsigned)i0;
#pragma unroll
    for (int s = 1; s < 64; s <<= 1) {
      const unsigned long long o = __shfl_xor(pk, s, 64);
      pk = (o < pk) ? o : pk;
    }
    const int widx = (int)(unsigned)(pk & 0xffffffffull);
    res[r] = widx;
    any |= (widx == l) ? 1 : 0;
    const bool win = (i0 == widx);
    d0 = win ? d1 : d0; i0 = win ? i1 : i0;
    d1 = win ? d2 : d1; i1 = win ? i2 : i1;
    d2 = win ? d3 : d2; i2 = win ? i3 : i2;
    d3 = win ? d4 : d3; i3 = win ? i4 : i3;
    d4 = win ? d5 : d4; i4 = win ? i5 : i4;
    d5 = win ? d6 : d5; i5 = win ? i6 : i5;
    d6 = win ? d7 : d6; i6 = win ? i7 : i6;
    d7 = win ? FLT_MAX : d7; i7 = win ? 0x7fffffff : i7;
  }

  if (lane == 0) {
    int* onb = nbr + (size_t)row * KN;
    int4* o4 = reinterpret_cast<int4*>(onb);
    o4[0] = make_int4(res[0], res[1], res[2], res[3]);
    o4[1] = make_int4(res[4], res[5], res[6], res[7]);
    o4[2] = make_int4(res[8], res[9], res[10], res[11]);
    o4[3] = make_int4(res[12], res[13], res[14], res[15]);
    isin[row] = any;
  }
}

// ---------------------------------------------------------------------------
// Kernel 2: bf16-MFMA GEMM with fused fp32->bf16(hi/lo) staging.
//   C[m,n] = A[m,:] . W[n,:] (+bias, epilogue)   A: Mx512 fp32, W: Ntotx512 fp32
// PASSES=1: plain bf16 (hi only).  PASSES=3: split hi/lo, 3 MFMA chains
//   (hi*hi + hi*lo + lo*hi) -> ~fp32 accuracy.
// Tile 128x128, BK=32, 4 waves (2x2 of 64x64), 16x16x32 MFMA.
// mode 0: scale cols < D by 0.125 (q scale). mode 1: isin-select vs X.
// ---------------------------------------------------------------------------
constexpr int BM = 128, BN = 128, BK = 32;
constexpr int LDT = 40;   // padded LDS row (80B stride -> 2-way bank alias, free)

template <int PASSES>
__global__ __launch_bounds__(256) void gemm_bf16(const float* __restrict__ A,
                                                 const float* __restrict__ W,
                                                 const float* __restrict__ bias,
                                                 float* __restrict__ C,
                                                 int Ntot, int mode,
                                                 const float* __restrict__ X,
                                                 const int* __restrict__ isin) {
  __shared__ unsigned short Ah[BM][LDT];
  __shared__ unsigned short Bh[BN][LDT];
  __shared__ unsigned short Al[PASSES == 3 ? BM : 1][LDT];
  __shared__ unsigned short Bl[PASSES == 3 ? BN : 1][LDT];

  const int tid = threadIdx.x;
  const int m0 = blockIdx.x * BM;
  const int n0 = blockIdx.y * BN;

  // staging map: thread -> (row, 16-col half) of the 128x32 tile
  const int srow = tid >> 1;
  const int scol = (tid & 1) * 16;
  const float* Aptr = A + (size_t)(m0 + srow) * D + scol;
  const float* Wptr = W + (size_t)(n0 + srow) * D + scol;

  // compute map
  const int wave = tid >> 6;
  const int lane = tid & 63;
  const int wr0 = (wave >> 1) * 64;
  const int wc0 = (wave & 1) * 64;
  const int fr_row = lane & 15;          // row-within-frag (A side) / col (B side)
  const int kof = (lane >> 4) * 8;       // k-offset of this lane's 8 bf16

  f32x4 acc[4][4];
#pragma unroll
  for (int i = 0; i < 4; ++i)
#pragma unroll
    for (int j = 0; j < 4; ++j) acc[i][j] = {0.f, 0.f, 0.f, 0.f};

  for (int k0 = 0; k0 < D; k0 += BK) {
    __syncthreads();   // previous iteration's reads complete
#pragma unroll
    for (int j = 0; j < 4; ++j) {
      const int c = scol + j * 4;
      {
        const float4 v = *reinterpret_cast<const float4*>(Aptr + k0 + j * 4);
        const unsigned short h0 = f2bf(v.x), h1 = f2bf(v.y), h2 = f2bf(v.z), h3 = f2bf(v.w);
        uint2 hp;
        hp.x = (unsigned)h0 | ((unsigned)h1 << 16);
        hp.y = (unsigned)h2 | ((unsigned)h3 << 16);
        *reinterpret_cast<uint2*>(&Ah[srow][c]) = hp;
        if constexpr (PASSES == 3) {
          const unsigned short l0 = f2bf(v.x - bf2f(h0)), l1 = f2bf(v.y - bf2f(h1));
          const unsigned short l2 = f2bf(v.z - bf2f(h2)), l3 = f2bf(v.w - bf2f(h3));
          uint2 lp;
          lp.x = (unsigned)l0 | ((unsigned)l1 << 16);
          lp.y = (unsigned)l2 | ((unsigned)l3 << 16);
          *reinterpret_cast<uint2*>(&Al[srow][c]) = lp;
        }
      }
      {
        const float4 v = *reinterpret_cast<const float4*>(Wptr + k0 + j * 4);
        const unsigned short h0 = f2bf(v.x), h1 = f2bf(v.y), h2 = f2bf(v.z), h3 = f2bf(v.w);
        uint2 hp;
        hp.x = (unsigned)h0 | ((unsigned)h1 << 16);
        hp.y = (unsigned)h2 | ((unsigned)h3 << 16);
        *reinterpret_cast<uint2*>(&Bh[srow][c]) = hp;
        if constexpr (PASSES == 3) {
          const unsigned short l0 = f2bf(v.x - bf2f(h0)), l1 = f2bf(v.y - bf2f(h1));
          const unsigned short l2 = f2bf(v.z - bf2f(h2)), l3 = f2bf(v.w - bf2f(h3));
          uint2 lp;
          lp.x = (unsigned)l0 | ((unsigned)l1 << 16);
          lp.y = (unsigned)l2 | ((unsigned)l3 << 16);
          *reinterpret_cast<uint2*>(&Bl[srow][c]) = lp;
        }
      }
    }
    __syncthreads();   // tile staged

    short8 ah[4], al[4];
#pragma unroll
    for (int fr = 0; fr < 4; ++fr) {
      ah[fr] = *reinterpret_cast<const short8*>(&Ah[wr0 + fr * 16 + fr_row][kof]);
      if constexpr (PASSES == 3)
        al[fr] = *reinterpret_cast<const short8*>(&Al[wr0 + fr * 16 + fr_row][kof]);
    }
#pragma unroll
    for (int fc = 0; fc < 4; ++fc) {
      const short8 bh = *reinterpret_cast<const short8*>(&Bh[wc0 + fc * 16 + fr_row][kof]);
      short8 bl;
      if constexpr (PASSES == 3)
        bl = *reinterpret_cast<const short8*>(&Bl[wc0 + fc * 16 + fr_row][kof]);
#pragma unroll
      for (int fr = 0; fr < 4; ++fr) {
        acc[fr][fc] = __builtin_amdgcn_mfma_f32_16x16x32_bf16(ah[fr], bh, acc[fr][fc], 0, 0, 0);
        if constexpr (PASSES == 3) {
          acc[fr][fc] = __builtin_amdgcn_mfma_f32_16x16x32_bf16(ah[fr], bl, acc[fr][fc], 0, 0, 0);
          acc[fr][fc] = __builtin_amdgcn_mfma_f32_16x16x32_bf16(al[fr], bh, acc[fr][fc], 0, 0, 0);
        }
      }
    }
  }

  // epilogue: C/D layout col=lane&15, row=(lane>>4)*4+r  [m89-verified]
  const float scl = (mode == 0 && n0 < D) ? 0.125f : 1.0f;
#pragma unroll
  for (int fr = 0; fr < 4; ++fr) {
#pragma unroll
    for (int r = 0; r < 4; ++r) {
      const int grow = m0 + wr0 + fr * 16 + (lane >> 4) * 4 + r;
      const int ok = (mode == 1) ? isin[grow] : 1;
#pragma unroll
      for (int fc = 0; fc < 4; ++fc) {
        const int gcol = n0 + wc0 + fc * 16 + (lane & 15);
        float v = (acc[fr][fc][r] + bias[gcol]) * scl;
        if (mode == 1 && !ok) v = X[(size_t)grow * D + gcol];
        C[(size_t)grow * (size_t)Ntot + gcol] = v;
      }
    }
  }
}

// ---------------------------------------------------------------------------
// Kernel 3: gathered 16-neighbor attention (unchanged, R2).
// ---------------------------------------------------------------------------
__global__ __launch_bounds__(256) void attn_kernel(const float* __restrict__ qkv,
                                                   const int* __restrict__ nbr,
                                                   float* __restrict__ ctx) {
  __shared__ float sc[4][NH][KN];
  const int wave = threadIdx.x >> 6;
  const int lane = threadIdx.x & 63;
  const int bl = blockIdx.x * 4 + wave;
  const int bbase = (bl >> 12) << 12;
  const int* nb = nbr + (size_t)bl * KN;

  const int h = lane >> 3;
  const int n0 = lane & 7;

  const float* q = qkv + (size_t)bl * N_IN + h * DH;
  float4 qr[16];
#pragma unroll
  for (int i = 0; i < 16; ++i)
    qr[i] = *reinterpret_cast<const float4*>(&q[i * 4]);

#pragma unroll
  for (int t = 0; t < 2; ++t) {
    const int n = n0 + t * 8;
    const int j = nb[n];
    const float* kr = qkv + (size_t)(bbase + j) * N_IN + D + h * DH;
    float a0 = 0.f, a1 = 0.f;
#pragma unroll
    for (int i = 0; i < 16; i += 2) {
      const float4 k0 = *reinterpret_cast<const float4*>(&kr[i * 4]);
      const float4 k1 = *reinterpret_cast<const float4*>(&kr[i * 4 + 4]);
      a0 = fmaf(qr[i].x, k0.x, a0); a0 = fmaf(qr[i].y, k0.y, a0);
      a0 = fmaf(qr[i].z, k0.z, a0); a0 = fmaf(qr[i].w, k0.w, a0);
      a1 = fmaf(qr[i + 1].x, k1.x, a1); a1 = fmaf(qr[i + 1].y, k1.y, a1);
      a1 = fmaf(qr[i + 1].z, k1.z, a1); a1 = fmaf(qr[i + 1].w, k1.w, a1);
    }
    sc[wave][h][n] = a0 + a1;
  }
  __syncthreads();

  float e[KN];
  float mx = -FLT_MAX;
#pragma unroll
  for (int n = 0; n < KN; ++n) mx = fmaxf(mx, sc[wave][h][n]);
  float sum = 0.f;
#pragma unroll
  for (int n = 0; n < KN; ++n) { e[n] = expf(sc[wave][h][n] - mx); sum += e[n]; }
  const float inv = 1.0f / sum;

  const int d0 = (lane & 7) * 8;
  float acc[8];
#pragma unroll
  for (int i = 0; i < 8; ++i) acc[i] = 0.f;
#pragma unroll
  for (int n = 0; n < KN; ++n) {
    const int j = nb[n];
    const float* vr = qkv + (size_t)(bbase + j) * N_IN + 2 * D + h * DH + d0;
    const float w = e[n] * inv;
    const float4 v0 = *reinterpret_cast<const float4*>(&vr[0]);
    const float4 v1 = *reinterpret_cast<const float4*>(&vr[4]);
    acc[0] = fmaf(w, v0.x, acc[0]); acc[1] = fmaf(w, v0.y, acc[1]);
    acc[2] = fmaf(w, v0.z, acc[2]); acc[3] = fmaf(w, v0.w, acc[3]);
    acc[4] = fmaf(w, v1.x, acc[4]); acc[5] = fmaf(w, v1.y, acc[5]);
    acc[6] = fmaf(w, v1.z, acc[6]); acc[7] = fmaf(w, v1.w, acc[7]);
  }
  float* cp = ctx + (size_t)bl * D + h * DH + d0;
  *reinterpret_cast<float4*>(&cp[0]) = make_float4(acc[0], acc[1], acc[2], acc[3]);
  *reinterpret_cast<float4*>(&cp[4]) = make_float4(acc[4], acc[5], acc[6], acc[7]);
}

// ---------------------------------------------------------------------------
extern "C" void kernel_launch(void* const* d_in, const int* in_sizes, int n_in,
                              void* d_out, int out_size, void* d_ws, size_t ws_size,
                              hipStream_t stream) {
  const float* x     = (const float*)d_in[0];
  const float* pos   = (const float*)d_in[1];
  const float* in_w  = (const float*)d_in[2];
  const float* in_b  = (const float*)d_in[3];
  const float* out_w = (const float*)d_in[4];
  const float* out_b = (const float*)d_in[5];
  float* out = (float*)d_out;

  const size_t nbr_bytes  = (size_t)M * KN * sizeof(int);
  const size_t isin_bytes = (size_t)M * sizeof(int);
  const size_t qkv_bytes  = (size_t)M * N_IN * sizeof(float);
  const size_t ctx_bytes  = (size_t)M * D * sizeof(float);
  const size_t need = nbr_bytes + isin_bytes + qkv_bytes + ctx_bytes + 1024;
  if (ws_size < need) return;

  char* w = (char*)d_ws;
  int*   nbr  = (int*)w;                 w += (nbr_bytes + 255) & ~(size_t)255;
  int*   isin = (int*)w;                 w += (isin_bytes + 255) & ~(size_t)255;
  float* qkv  = (float*)w;               w += (qkv_bytes + 255) & ~(size_t)255;
  float* ctx  = (float*)w;

  // 1) top-k neighbors
  topk_kernel<<<B * (L / 4), 256, 0, stream>>>(pos, nbr, isin);

  // 2) in_proj (plain bf16: downstream attenuation keeps error ~5e-4)
  gemm_bf16<1><<<dim3(M / BM, N_IN / BN), 256, 0, stream>>>(
      x, in_w, in_b, qkv, N_IN, 0, nullptr, nullptr);

  // 3) gathered neighbor attention -> ctx
  attn_kernel<<<M / 4, 256, 0, stream>>>(qkv, nbr, ctx);

  // 4) out_proj (split 3-pass: error hits output directly -> keep ~fp32)
  gemm_bf16<3><<<dim3(M / BM, D / BN), 256, 0, stream>>>(
      ctx, out_w, out_b, out, D, 1, x, isin);
}

// Round 4
// 288.233 us; speedup vs baseline: 5.5024x; 1.5567x over previous
//
#include <hip/hip_runtime.h>
#include <cfloat>
#include <cmath>

constexpr int B = 4;
constexpr int L = 4096;
constexpr int D = 512;
constexpr int NH = 8;
constexpr int DH = 64;
constexpr int KN = 16;
constexpr int M = B * L;          // 16384 rows
constexpr int N_IN = 3 * D;       // 1536

typedef __attribute__((ext_vector_type(8))) short short8;   // 8 bf16 = 4 VGPR
typedef __attribute__((ext_vector_type(4))) float f32x4;    // MFMA acc
typedef unsigned short ushort;

__device__ __forceinline__ ushort f2bf(float f) {   // RN-even bf16
  unsigned u = __float_as_uint(f);
  u = u + 0x7fffu + ((u >> 16) & 1u);
  return (ushort)(u >> 16);
}
__device__ __forceinline__ float bf2f(ushort h) {
  return __uint_as_float(((unsigned)h) << 16);
}
__device__ __forceinline__ float dot8(const uint4 qu, const uint4 ku, float a) {
  a = fmaf(bf2f((ushort)qu.x), bf2f((ushort)ku.x), a);
  a = fmaf(bf2f((ushort)(qu.x >> 16)), bf2f((ushort)(ku.x >> 16)), a);
  a = fmaf(bf2f((ushort)qu.y), bf2f((ushort)ku.y), a);
  a = fmaf(bf2f((ushort)(qu.y >> 16)), bf2f((ushort)(ku.y >> 16)), a);
  a = fmaf(bf2f((ushort)qu.z), bf2f((ushort)ku.z), a);
  a = fmaf(bf2f((ushort)(qu.z >> 16)), bf2f((ushort)(ku.z >> 16)), a);
  a = fmaf(bf2f((ushort)qu.w), bf2f((ushort)ku.w), a);
  a = fmaf(bf2f((ushort)(qu.w >> 16)), bf2f((ushort)(ku.w >> 16)), a);
  return a;
}

// ---------------------------------------------------------------------------
// Kernel 1: top-16 nearest neighbors, one WAVE per query (unchanged, R2).
// ---------------------------------------------------------------------------
__global__ __launch_bounds__(256) void topk_kernel(const float* __restrict__ pos,
                                                   int* __restrict__ nbr,
                                                   int* __restrict__ isin) {
  __shared__ float sx[L], sy[L], sz[L];   // 48 KB
  const int wave = threadIdx.x >> 6;
  const int lane = threadIdx.x & 63;
  const int b = blockIdx.x >> 10;
  const int blk = blockIdx.x & 1023;
  const int l = blk * 4 + wave;
  const int row = b * L + l;

  const float* p = pos + (size_t)b * L * 3;
  for (int i = threadIdx.x; i < L; i += 256) {
    sx[i] = p[3 * i + 0];
    sy[i] = p[3 * i + 1];
    sz[i] = p[3 * i + 2];
  }
  __syncthreads();

  const float qx = sx[l], qy = sy[l], qz = sz[l];

  float d0 = FLT_MAX, d1 = FLT_MAX, d2 = FLT_MAX, d3 = FLT_MAX;
  float d4 = FLT_MAX, d5 = FLT_MAX, d6 = FLT_MAX, d7 = FLT_MAX;
  int i0 = 0x7fffffff, i1 = 0x7fffffff, i2 = 0x7fffffff, i3 = 0x7fffffff;
  int i4 = 0x7fffffff, i5 = 0x7fffffff, i6 = 0x7fffffff, i7 = 0x7fffffff;

#pragma unroll 4
  for (int j = 0; j < 64; ++j) {
    const int c = j * 64 + lane;
    const float dx = qx - sx[c];
    const float dy = qy - sy[c];
    const float dz = qz - sz[c];
    float cd = sqrtf(fmaf(dx, dx, fmaf(dy, dy, dz * dz)));
    int ci = c;
#define INS(dd, ii)                                        \
    {                                                      \
      const bool lt = cd < dd;                             \
      const float nd = lt ? cd : dd;                       \
      const int ni = lt ? ci : ii;                         \
      const float xd = lt ? dd : cd;                       \
      const int xi = lt ? ii : ci;                         \
      dd = nd; ii = ni; cd = xd; ci = xi;                  \
    }
    INS(d0, i0) INS(d1, i1) INS(d2, i2) INS(d3, i3)
    INS(d4, i4) INS(d5, i5) INS(d6, i6) INS(d7, i7)
#undef INS
  }

  int res[KN];
  int any = 0;
#pragma unroll
  for (int r = 0; r < KN; ++r) {
    unsigned long long pk =
        ((unsigned long long)__float_as_uint(d0) << 32) | (unsigned)i0;
#pragma unroll
    for (int s = 1; s < 64; s <<= 1) {
      const unsigned long long o = __shfl_xor(pk, s, 64);
      pk = (o < pk) ? o : pk;
    }
    const int widx = (int)(unsigned)(pk & 0xffffffffull);
    res[r] = widx;
    any |= (widx == l) ? 1 : 0;
    const bool win = (i0 == widx);
    d0 = win ? d1 : d0; i0 = win ? i1 : i0;
    d1 = win ? d2 : d1; i1 = win ? i2 : i1;
    d2 = win ? d3 : d2; i2 = win ? i3 : i2;
    d3 = win ? d4 : d3; i3 = win ? i4 : i3;
    d4 = win ? d5 : d4; i4 = win ? i5 : i4;
    d5 = win ? d6 : d5; i5 = win ? i6 : i5;
    d6 = win ? d7 : d6; i6 = win ? i7 : i6;
    d7 = win ? FLT_MAX : d7; i7 = win ? 0x7fffffff : i7;
  }

  if (lane == 0) {
    int* onb = nbr + (size_t)row * KN;
    int4* o4 = reinterpret_cast<int4*>(onb);
    o4[0] = make_int4(res[0], res[1], res[2], res[3]);
    o4[1] = make_int4(res[4], res[5], res[6], res[7]);
    o4[2] = make_int4(res[8], res[9], res[10], res[11]);
    o4[3] = make_int4(res[12], res[13], res[14], res[15]);
    isin[row] = any;
  }
}

// ---------------------------------------------------------------------------
// GEMM tiles: 128x128, BK=32, 4 waves (2x2 of 64x64), 16x16x32 bf16 MFMA.
// C/D layout col=lane&15, row=(lane>>4)*4+r  [m89-verified]
// ---------------------------------------------------------------------------
constexpr int BM = 128, BN = 128, BK = 32;
constexpr int LDT = 40;   // padded LDS row (80B stride -> 2-way alias, free)

// Kernel 2a: in_proj. A,W fp32 -> plain bf16 MFMA; epilogue writes bf16 into
// split Q (pre-scaled by 0.125), K, V buffers [M][512].
__global__ __launch_bounds__(256) void gemm_in(const float* __restrict__ A,
                                               const float* __restrict__ W,
                                               const float* __restrict__ bias,
                                               ushort* __restrict__ qb,
                                               ushort* __restrict__ kb,
                                               ushort* __restrict__ vb) {
  __shared__ ushort Ah[BM][LDT];
  __shared__ ushort Bh[BN][LDT];

  const int tid = threadIdx.x;
  const int m0 = blockIdx.x * BM;
  const int n0 = blockIdx.y * BN;

  const int srow = tid >> 1;
  const int scol = (tid & 1) * 16;
  const float* Aptr = A + (size_t)(m0 + srow) * D + scol;
  const float* Wptr = W + (size_t)(n0 + srow) * D + scol;

  const int wave = tid >> 6;
  const int lane = tid & 63;
  const int wr0 = (wave >> 1) * 64;
  const int wc0 = (wave & 1) * 64;
  const int fr_row = lane & 15;
  const int kof = (lane >> 4) * 8;

  f32x4 acc[4][4];
#pragma unroll
  for (int i = 0; i < 4; ++i)
#pragma unroll
    for (int j = 0; j < 4; ++j) acc[i][j] = {0.f, 0.f, 0.f, 0.f};

  for (int k0 = 0; k0 < D; k0 += BK) {
    __syncthreads();
#pragma unroll
    for (int j = 0; j < 4; ++j) {
      const int c = scol + j * 4;
      {
        const float4 v = *reinterpret_cast<const float4*>(Aptr + k0 + j * 4);
        uint2 hp;
        hp.x = (unsigned)f2bf(v.x) | ((unsigned)f2bf(v.y) << 16);
        hp.y = (unsigned)f2bf(v.z) | ((unsigned)f2bf(v.w) << 16);
        *reinterpret_cast<uint2*>(&Ah[srow][c]) = hp;
      }
      {
        const float4 v = *reinterpret_cast<const float4*>(Wptr + k0 + j * 4);
        uint2 hp;
        hp.x = (unsigned)f2bf(v.x) | ((unsigned)f2bf(v.y) << 16);
        hp.y = (unsigned)f2bf(v.z) | ((unsigned)f2bf(v.w) << 16);
        *reinterpret_cast<uint2*>(&Bh[srow][c]) = hp;
      }
    }
    __syncthreads();

    short8 ah[4];
#pragma unroll
    for (int fr = 0; fr < 4; ++fr)
      ah[fr] = *reinterpret_cast<const short8*>(&Ah[wr0 + fr * 16 + fr_row][kof]);
#pragma unroll
    for (int fc = 0; fc < 4; ++fc) {
      const short8 bh = *reinterpret_cast<const short8*>(&Bh[wc0 + fc * 16 + fr_row][kof]);
#pragma unroll
      for (int fr = 0; fr < 4; ++fr)
        acc[fr][fc] = __builtin_amdgcn_mfma_f32_16x16x32_bf16(ah[fr], bh, acc[fr][fc], 0, 0, 0);
    }
  }

  const int region = n0 >> 9;             // 0=q, 1=k, 2=v (BN=128 stays inside)
  ushort* outb = region == 0 ? qb : (region == 1 ? kb : vb);
  const float scl = region == 0 ? 0.125f : 1.0f;
  const int nloc0 = (n0 & 511) + wc0;
#pragma unroll
  for (int fr = 0; fr < 4; ++fr) {
#pragma unroll
    for (int r = 0; r < 4; ++r) {
      const int grow = m0 + wr0 + fr * 16 + (lane >> 4) * 4 + r;
#pragma unroll
      for (int fc = 0; fc < 4; ++fc) {
        const int cc = fc * 16 + (lane & 15);
        const float v = (acc[fr][fc][r] + bias[n0 + wc0 + cc]) * scl;
        outb[(size_t)grow * D + nloc0 + cc] = f2bf(v);
      }
    }
  }
}

// Kernel 2b: out_proj. A = ctx (bf16, staged directly), W fp32 split hi/lo
// (2 MFMA chains -> ~fp32 accuracy). Epilogue: isin-select vs X, fp32 out.
__global__ __launch_bounds__(256) void gemm_out(const ushort* __restrict__ A,
                                                const float* __restrict__ W,
                                                const float* __restrict__ bias,
                                                float* __restrict__ C,
                                                const float* __restrict__ X,
                                                const int* __restrict__ isin) {
  __shared__ ushort Ah[BM][LDT];
  __shared__ ushort Bh[BN][LDT];
  __shared__ ushort Bl[BN][LDT];

  const int tid = threadIdx.x;
  const int m0 = blockIdx.x * BM;
  const int n0 = blockIdx.y * BN;

  const int srow = tid >> 1;
  const int scol = (tid & 1) * 16;
  const ushort* Aptr = A + (size_t)(m0 + srow) * D + scol;
  const float* Wptr = W + (size_t)(n0 + srow) * D + scol;

  const int wave = tid >> 6;
  const int lane = tid & 63;
  const int wr0 = (wave >> 1) * 64;
  const int wc0 = (wave & 1) * 64;
  const int fr_row = lane & 15;
  const int kof = (lane >> 4) * 8;

  f32x4 acc[4][4];
#pragma unroll
  for (int i = 0; i < 4; ++i)
#pragma unroll
    for (int j = 0; j < 4; ++j) acc[i][j] = {0.f, 0.f, 0.f, 0.f};

  for (int k0 = 0; k0 < D; k0 += BK) {
    __syncthreads();
    {
      const uint4* s = reinterpret_cast<const uint4*>(Aptr + k0);
      *reinterpret_cast<uint4*>(&Ah[srow][scol]) = s[0];
      *reinterpret_cast<uint4*>(&Ah[srow][scol + 8]) = s[1];
    }
#pragma unroll
    for (int j = 0; j < 4; ++j) {
      const int c = scol + j * 4;
      const float4 v = *reinterpret_cast<const float4*>(Wptr + k0 + j * 4);
      const ushort h0 = f2bf(v.x), h1 = f2bf(v.y), h2 = f2bf(v.z), h3 = f2bf(v.w);
      uint2 hp, lp;
      hp.x = (unsigned)h0 | ((unsigned)h1 << 16);
      hp.y = (unsigned)h2 | ((unsigned)h3 << 16);
      lp.x = (unsigned)f2bf(v.x - bf2f(h0)) | ((unsigned)f2bf(v.y - bf2f(h1)) << 16);
      lp.y = (unsigned)f2bf(v.z - bf2f(h2)) | ((unsigned)f2bf(v.w - bf2f(h3)) << 16);
      *reinterpret_cast<uint2*>(&Bh[srow][c]) = hp;
      *reinterpret_cast<uint2*>(&Bl[srow][c]) = lp;
    }
    __syncthreads();

    short8 ah[4];
#pragma unroll
    for (int fr = 0; fr < 4; ++fr)
      ah[fr] = *reinterpret_cast<const short8*>(&Ah[wr0 + fr * 16 + fr_row][kof]);
#pragma unroll
    for (int fc = 0; fc < 4; ++fc) {
      const short8 bh = *reinterpret_cast<const short8*>(&Bh[wc0 + fc * 16 + fr_row][kof]);
      const short8 bl = *reinterpret_cast<const short8*>(&Bl[wc0 + fc * 16 + fr_row][kof]);
#pragma unroll
      for (int fr = 0; fr < 4; ++fr) {
        acc[fr][fc] = __builtin_amdgcn_mfma_f32_16x16x32_bf16(ah[fr], bh, acc[fr][fc], 0, 0, 0);
        acc[fr][fc] = __builtin_amdgcn_mfma_f32_16x16x32_bf16(ah[fr], bl, acc[fr][fc], 0, 0, 0);
      }
    }
  }

#pragma unroll
  for (int fr = 0; fr < 4; ++fr) {
#pragma unroll
    for (int r = 0; r < 4; ++r) {
      const int grow = m0 + wr0 + fr * 16 + (lane >> 4) * 4 + r;
      const int ok = isin[grow];
#pragma unroll
      for (int fc = 0; fc < 4; ++fc) {
        const int gcol = n0 + wc0 + fc * 16 + (lane & 15);
        float v = acc[fr][fc][r] + bias[gcol];
        if (!ok) v = X[(size_t)grow * D + gcol];
        C[(size_t)grow * D + gcol] = v;
      }
    }
  }
}

// ---------------------------------------------------------------------------
// Kernel 3: gathered 16-neighbor attention, bf16 K/V/Q, fp32 accumulate.
// One wave per (b,l); 4 waves/block. h = lane>>3; phase1 n = (lane&7)+8t.
// ---------------------------------------------------------------------------
__global__ __launch_bounds__(256) void attn_kernel(const ushort* __restrict__ qb,
                                                   const ushort* __restrict__ kb,
                                                   const ushort* __restrict__ vb,
                                                   const int* __restrict__ nbr,
                                                   ushort* __restrict__ ctx) {
  __shared__ float sc[4][NH][KN];
  const int wave = threadIdx.x >> 6;
  const int lane = threadIdx.x & 63;
  const int bl = blockIdx.x * 4 + wave;
  const int bbase = (bl >> 12) << 12;          // b * L
  const int* nb = nbr + (size_t)bl * KN;

  const int h = lane >> 3;
  const int n0 = lane & 7;

  const ushort* qp = qb + (size_t)bl * D + h * DH;
  uint4 qv[8];
#pragma unroll
  for (int i = 0; i < 8; ++i)
    qv[i] = *reinterpret_cast<const uint4*>(qp + i * 8);

#pragma unroll
  for (int t = 0; t < 2; ++t) {
    const int j = nb[n0 + t * 8];
    const ushort* kr = kb + (size_t)(bbase + j) * D + h * DH;
    float a = 0.f;
#pragma unroll
    for (int i = 0; i < 8; ++i)
      a = dot8(qv[i], *reinterpret_cast<const uint4*>(kr + i * 8), a);
    sc[wave][h][n0 + t * 8] = a;
  }
  __syncthreads();

  float e[KN];
  float mx = -FLT_MAX;
#pragma unroll
  for (int n = 0; n < KN; ++n) mx = fmaxf(mx, sc[wave][h][n]);
  float sum = 0.f;
#pragma unroll
  for (int n = 0; n < KN; ++n) { e[n] = expf(sc[wave][h][n] - mx); sum += e[n]; }
  const float inv = 1.0f / sum;

  const int d0 = (lane & 7) * 8;
  float acc[8];
#pragma unroll
  for (int i = 0; i < 8; ++i) acc[i] = 0.f;
#pragma unroll
  for (int n = 0; n < KN; ++n) {
    const int j = nb[n];
    const uint4 vv = *reinterpret_cast<const uint4*>(
        vb + (size_t)(bbase + j) * D + h * DH + d0);
    const float w = e[n] * inv;
    acc[0] = fmaf(w, bf2f((ushort)vv.x), acc[0]);
    acc[1] = fmaf(w, bf2f((ushort)(vv.x >> 16)), acc[1]);
    acc[2] = fmaf(w, bf2f((ushort)vv.y), acc[2]);
    acc[3] = fmaf(w, bf2f((ushort)(vv.y >> 16)), acc[3]);
    acc[4] = fmaf(w, bf2f((ushort)vv.z), acc[4]);
    acc[5] = fmaf(w, bf2f((ushort)(vv.z >> 16)), acc[5]);
    acc[6] = fmaf(w, bf2f((ushort)vv.w), acc[6]);
    acc[7] = fmaf(w, bf2f((ushort)(vv.w >> 16)), acc[7]);
  }
  uint4 o;
  o.x = (unsigned)f2bf(acc[0]) | ((unsigned)f2bf(acc[1]) << 16);
  o.y = (unsigned)f2bf(acc[2]) | ((unsigned)f2bf(acc[3]) << 16);
  o.z = (unsigned)f2bf(acc[4]) | ((unsigned)f2bf(acc[5]) << 16);
  o.w = (unsigned)f2bf(acc[6]) | ((unsigned)f2bf(acc[7]) << 16);
  *reinterpret_cast<uint4*>(ctx + (size_t)bl * D + h * DH + d0) = o;
}

// ---------------------------------------------------------------------------
extern "C" void kernel_launch(void* const* d_in, const int* in_sizes, int n_in,
                              void* d_out, int out_size, void* d_ws, size_t ws_size,
                              hipStream_t stream) {
  const float* x     = (const float*)d_in[0];
  const float* pos   = (const float*)d_in[1];
  const float* in_w  = (const float*)d_in[2];
  const float* in_b  = (const float*)d_in[3];
  const float* out_w = (const float*)d_in[4];
  const float* out_b = (const float*)d_in[5];
  float* out = (float*)d_out;

  const size_t nbr_bytes  = (size_t)M * KN * sizeof(int);   // 1 MB
  const size_t isin_bytes = (size_t)M * sizeof(int);        // 64 KB
  const size_t half_bytes = (size_t)M * D * sizeof(ushort); // 16.8 MB each
  const size_t need = nbr_bytes + isin_bytes + 4 * half_bytes + 4096;
  if (ws_size < need) return;

  char* w = (char*)d_ws;
  int*    nbr  = (int*)w;    w += (nbr_bytes + 255) & ~(size_t)255;
  int*    isin = (int*)w;    w += (isin_bytes + 255) & ~(size_t)255;
  ushort* qb   = (ushort*)w; w += (half_bytes + 255) & ~(size_t)255;
  ushort* kb   = (ushort*)w; w += (half_bytes + 255) & ~(size_t)255;
  ushort* vb   = (ushort*)w; w += (half_bytes + 255) & ~(size_t)255;
  ushort* ctxb = (ushort*)w;

  // 1) top-k neighbors
  topk_kernel<<<B * (L / 4), 256, 0, stream>>>(pos, nbr, isin);

  // 2) in_proj -> bf16 Q(scaled)/K/V
  gemm_in<<<dim3(M / BM, N_IN / BN), 256, 0, stream>>>(x, in_w, in_b, qb, kb, vb);

  // 3) gathered neighbor attention -> bf16 ctx
  attn_kernel<<<M / 4, 256, 0, stream>>>(qb, kb, vb, nbr, ctxb);

  // 4) out_proj (A bf16 direct, W hi/lo 2-pass) + isin select
  gemm_out<<<dim3(M / BM, D / BN), 256, 0, stream>>>(ctxb, out_w, out_b, out, x, isin);
}

// Round 5
// 272.728 us; speedup vs baseline: 5.8152x; 1.0569x over previous
//
#include <hip/hip_runtime.h>
#include <cfloat>
#include <cmath>

constexpr int B = 4;
constexpr int L = 4096;
constexpr int D = 512;
constexpr int NH = 8;
constexpr int DH = 64;
constexpr int KN = 16;
constexpr int M = B * L;          // 16384 rows
constexpr int N_IN = 3 * D;       // 1536

typedef __attribute__((ext_vector_type(8))) short short8;   // 8 bf16 = 4 VGPR
typedef __attribute__((ext_vector_type(4))) float f32x4;    // MFMA acc
typedef unsigned short ushort;

__device__ __forceinline__ ushort f2bf(float f) {   // RN-even bf16
  unsigned u = __float_as_uint(f);
  u = u + 0x7fffu + ((u >> 16) & 1u);
  return (ushort)(u >> 16);
}
__device__ __forceinline__ float bf2f(ushort h) {
  return __uint_as_float(((unsigned)h) << 16);
}
__device__ __forceinline__ float dot8(const uint4 qu, const uint4 ku, float a) {
  a = fmaf(bf2f((ushort)qu.x), bf2f((ushort)ku.x), a);
  a = fmaf(bf2f((ushort)(qu.x >> 16)), bf2f((ushort)(ku.x >> 16)), a);
  a = fmaf(bf2f((ushort)qu.y), bf2f((ushort)ku.y), a);
  a = fmaf(bf2f((ushort)(qu.y >> 16)), bf2f((ushort)(ku.y >> 16)), a);
  a = fmaf(bf2f((ushort)qu.z), bf2f((ushort)ku.z), a);
  a = fmaf(bf2f((ushort)(qu.z >> 16)), bf2f((ushort)(ku.z >> 16)), a);
  a = fmaf(bf2f((ushort)qu.w), bf2f((ushort)ku.w), a);
  a = fmaf(bf2f((ushort)(qu.w >> 16)), bf2f((ushort)(ku.w >> 16)), a);
  return a;
}

// ---------------------------------------------------------------------------
// Kernel 1: top-16 NN, threshold-pruned two-phase. One wave per query,
// 8 waves/block, positions staged as float4 in LDS (ds_read_b128).
// Phase A: per-lane min dist. Threshold: 16th-smallest lane-min via binary
// search on float bits (keep dbits < P retains the exact top-16: lanes
// holding top-16 members have min <= d16; others have min >= d17).
// Phase B: append survivors (~20/wave) to per-wave LDS list (LDS atomic).
// Rank by exact packed (dist_bits,idx) u64 -> lax.top_k order bit-exact.
// ---------------------------------------------------------------------------
__global__ __launch_bounds__(512) void topk_kernel(const float* __restrict__ pos,
                                                   int* __restrict__ nbr,
                                                   int* __restrict__ isin) {
  __shared__ float4 sp[L];                    // 64 KB
  __shared__ unsigned long long lst[8 * 64];  // 4 KB
  __shared__ int scnt[8];
  const int wave = threadIdx.x >> 6;
  const int lane = threadIdx.x & 63;
  const int b = blockIdx.x >> 9;              // 512 blocks per batch
  const int l = (blockIdx.x & 511) * 8 + wave;
  const int row = b * L + l;

  const float* p = pos + (size_t)b * L * 3;
  for (int i = threadIdx.x; i < L; i += 512)
    sp[i] = make_float4(p[3 * i], p[3 * i + 1], p[3 * i + 2], 0.f);
  __syncthreads();

  const float4 q = sp[l];

  // phase A: per-lane min distance (identical op sequence to phase B)
  float m = FLT_MAX;
#pragma unroll 4
  for (int j = 0; j < 64; ++j) {
    const float4 c4 = sp[j * 64 + lane];
    const float dx = q.x - c4.x, dy = q.y - c4.y, dz = q.z - c4.z;
    m = fminf(m, sqrtf(fmaf(dx, dx, fmaf(dy, dy, dz * dz))));
  }
  const unsigned mbits = __float_as_uint(m);   // dist >= 0: uint cmp == float cmp

  // smallest P with |{lane-min bits < P}| >= 16  (wave-uniform scalar loop)
  unsigned lo = 1, hi = 0x40000000u;           // dist <= sqrt(3) < 2.0
  while (lo < hi) {
    const unsigned mid = (lo + hi) >> 1;
    const int c = __popcll(__ballot(mbits < mid));
    if (c >= 16) hi = mid; else lo = mid + 1;
  }
  const unsigned P = lo;                        // keep dbits < P  (= dist <= T16)

  if (lane == 0) scnt[wave] = 0;

  // phase B: collect survivors
#pragma unroll 4
  for (int j = 0; j < 64; ++j) {
    const int c = j * 64 + lane;
    const float4 c4 = sp[c];
    const float dx = q.x - c4.x, dy = q.y - c4.y, dz = q.z - c4.z;
    const float d = sqrtf(fmaf(dx, dx, fmaf(dy, dy, dz * dz)));
    const unsigned db = __float_as_uint(d);
    if (db < P) {
      const int slot = atomicAdd(&scnt[wave], 1);
      if (slot < 64)
        lst[wave * 64 + slot] = ((unsigned long long)db << 32) | (unsigned)c;
    }
  }
  const int n = min(scnt[wave], 64);            // n >= 16 guaranteed

  // exact rank among survivors: (dist asc, idx asc) == lax.top_k order
  const unsigned long long mine = (lane < n) ? lst[wave * 64 + lane] : ~0ull;
  int r = 0;
  for (int i = 0; i < n; ++i) r += (lst[wave * 64 + i] < mine) ? 1 : 0;

  const int idx = (int)(unsigned)(mine & 0xffffffffu);
  const bool wr = (lane < n) && (r < 16);
  if (wr) nbr[(size_t)row * KN + r] = idx;
  const unsigned long long hit = __ballot(wr && idx == l);
  if (lane == 0) isin[row] = hit ? 1 : 0;
}

// ---------------------------------------------------------------------------
// GEMM tiles: 128x128, BK=32, 4 waves (2x2 of 64x64), 16x16x32 bf16 MFMA.
// C/D layout col=lane&15, row=(lane>>4)*4+r  [m89-verified]
// ---------------------------------------------------------------------------
constexpr int BM = 128, BN = 128, BK = 32;
constexpr int LDT = 40;   // padded LDS row (80B stride -> 2-way alias, free)

// Kernel 2a: in_proj. A,W fp32 -> plain bf16 MFMA; epilogue writes bf16 into
// split Q (pre-scaled by 0.125), K, V buffers [M][512].
__global__ __launch_bounds__(256) void gemm_in(const float* __restrict__ A,
                                               const float* __restrict__ W,
                                               const float* __restrict__ bias,
                                               ushort* __restrict__ qb,
                                               ushort* __restrict__ kb,
                                               ushort* __restrict__ vb) {
  __shared__ ushort Ah[BM][LDT];
  __shared__ ushort Bh[BN][LDT];

  const int tid = threadIdx.x;
  const int m0 = blockIdx.x * BM;
  const int n0 = blockIdx.y * BN;

  const int srow = tid >> 1;
  const int scol = (tid & 1) * 16;
  const float* Aptr = A + (size_t)(m0 + srow) * D + scol;
  const float* Wptr = W + (size_t)(n0 + srow) * D + scol;

  const int wave = tid >> 6;
  const int lane = tid & 63;
  const int wr0 = (wave >> 1) * 64;
  const int wc0 = (wave & 1) * 64;
  const int fr_row = lane & 15;
  const int kof = (lane >> 4) * 8;

  f32x4 acc[4][4];
#pragma unroll
  for (int i = 0; i < 4; ++i)
#pragma unroll
    for (int j = 0; j < 4; ++j) acc[i][j] = {0.f, 0.f, 0.f, 0.f};

  for (int k0 = 0; k0 < D; k0 += BK) {
    __syncthreads();
#pragma unroll
    for (int j = 0; j < 4; ++j) {
      const int c = scol + j * 4;
      {
        const float4 v = *reinterpret_cast<const float4*>(Aptr + k0 + j * 4);
        uint2 hp;
        hp.x = (unsigned)f2bf(v.x) | ((unsigned)f2bf(v.y) << 16);
        hp.y = (unsigned)f2bf(v.z) | ((unsigned)f2bf(v.w) << 16);
        *reinterpret_cast<uint2*>(&Ah[srow][c]) = hp;
      }
      {
        const float4 v = *reinterpret_cast<const float4*>(Wptr + k0 + j * 4);
        uint2 hp;
        hp.x = (unsigned)f2bf(v.x) | ((unsigned)f2bf(v.y) << 16);
        hp.y = (unsigned)f2bf(v.z) | ((unsigned)f2bf(v.w) << 16);
        *reinterpret_cast<uint2*>(&Bh[srow][c]) = hp;
      }
    }
    __syncthreads();

    short8 ah[4];
#pragma unroll
    for (int fr = 0; fr < 4; ++fr)
      ah[fr] = *reinterpret_cast<const short8*>(&Ah[wr0 + fr * 16 + fr_row][kof]);
#pragma unroll
    for (int fc = 0; fc < 4; ++fc) {
      const short8 bh = *reinterpret_cast<const short8*>(&Bh[wc0 + fc * 16 + fr_row][kof]);
#pragma unroll
      for (int fr = 0; fr < 4; ++fr)
        acc[fr][fc] = __builtin_amdgcn_mfma_f32_16x16x32_bf16(ah[fr], bh, acc[fr][fc], 0, 0, 0);
    }
  }

  const int region = n0 >> 9;             // 0=q, 1=k, 2=v (BN=128 stays inside)
  ushort* outb = region == 0 ? qb : (region == 1 ? kb : vb);
  const float scl = region == 0 ? 0.125f : 1.0f;
  const int nloc0 = (n0 & 511) + wc0;
#pragma unroll
  for (int fr = 0; fr < 4; ++fr) {
#pragma unroll
    for (int r = 0; r < 4; ++r) {
      const int grow = m0 + wr0 + fr * 16 + (lane >> 4) * 4 + r;
#pragma unroll
      for (int fc = 0; fc < 4; ++fc) {
        const int cc = fc * 16 + (lane & 15);
        const float v = (acc[fr][fc][r] + bias[n0 + wc0 + cc]) * scl;
        outb[(size_t)grow * D + nloc0 + cc] = f2bf(v);
      }
    }
  }
}

// Kernel 2b: out_proj. A = ctx (bf16, staged directly), W fp32 split hi/lo
// (2 MFMA chains -> ~fp32 accuracy). Epilogue: isin-select vs X, fp32 out.
__global__ __launch_bounds__(256) void gemm_out(const ushort* __restrict__ A,
                                                const float* __restrict__ W,
                                                const float* __restrict__ bias,
                                                float* __restrict__ C,
                                                const float* __restrict__ X,
                                                const int* __restrict__ isin) {
  __shared__ ushort Ah[BM][LDT];
  __shared__ ushort Bh[BN][LDT];
  __shared__ ushort Bl[BN][LDT];

  const int tid = threadIdx.x;
  const int m0 = blockIdx.x * BM;
  const int n0 = blockIdx.y * BN;

  const int srow = tid >> 1;
  const int scol = (tid & 1) * 16;
  const ushort* Aptr = A + (size_t)(m0 + srow) * D + scol;
  const float* Wptr = W + (size_t)(n0 + srow) * D + scol;

  const int wave = tid >> 6;
  const int lane = tid & 63;
  const int wr0 = (wave >> 1) * 64;
  const int wc0 = (wave & 1) * 64;
  const int fr_row = lane & 15;
  const int kof = (lane >> 4) * 8;

  f32x4 acc[4][4];
#pragma unroll
  for (int i = 0; i < 4; ++i)
#pragma unroll
    for (int j = 0; j < 4; ++j) acc[i][j] = {0.f, 0.f, 0.f, 0.f};

  for (int k0 = 0; k0 < D; k0 += BK) {
    __syncthreads();
    {
      const uint4* s = reinterpret_cast<const uint4*>(Aptr + k0);
      *reinterpret_cast<uint4*>(&Ah[srow][scol]) = s[0];
      *reinterpret_cast<uint4*>(&Ah[srow][scol + 8]) = s[1];
    }
#pragma unroll
    for (int j = 0; j < 4; ++j) {
      const int c = scol + j * 4;
      const float4 v = *reinterpret_cast<const float4*>(Wptr + k0 + j * 4);
      const ushort h0 = f2bf(v.x), h1 = f2bf(v.y), h2 = f2bf(v.z), h3 = f2bf(v.w);
      uint2 hp, lp;
      hp.x = (unsigned)h0 | ((unsigned)h1 << 16);
      hp.y = (unsigned)h2 | ((unsigned)h3 << 16);
      lp.x = (unsigned)f2bf(v.x - bf2f(h0)) | ((unsigned)f2bf(v.y - bf2f(h1)) << 16);
      lp.y = (unsigned)f2bf(v.z - bf2f(h2)) | ((unsigned)f2bf(v.w - bf2f(h3)) << 16);
      *reinterpret_cast<uint2*>(&Bh[srow][c]) = hp;
      *reinterpret_cast<uint2*>(&Bl[srow][c]) = lp;
    }
    __syncthreads();

    short8 ah[4];
#pragma unroll
    for (int fr = 0; fr < 4; ++fr)
      ah[fr] = *reinterpret_cast<const short8*>(&Ah[wr0 + fr * 16 + fr_row][kof]);
#pragma unroll
    for (int fc = 0; fc < 4; ++fc) {
      const short8 bh = *reinterpret_cast<const short8*>(&Bh[wc0 + fc * 16 + fr_row][kof]);
      const short8 bl = *reinterpret_cast<const short8*>(&Bl[wc0 + fc * 16 + fr_row][kof]);
#pragma unroll
      for (int fr = 0; fr < 4; ++fr) {
        acc[fr][fc] = __builtin_amdgcn_mfma_f32_16x16x32_bf16(ah[fr], bh, acc[fr][fc], 0, 0, 0);
        acc[fr][fc] = __builtin_amdgcn_mfma_f32_16x16x32_bf16(ah[fr], bl, acc[fr][fc], 0, 0, 0);
      }
    }
  }

#pragma unroll
  for (int fr = 0; fr < 4; ++fr) {
#pragma unroll
    for (int r = 0; r < 4; ++r) {
      const int grow = m0 + wr0 + fr * 16 + (lane >> 4) * 4 + r;
      const int ok = isin[grow];
#pragma unroll
      for (int fc = 0; fc < 4; ++fc) {
        const int gcol = n0 + wc0 + fc * 16 + (lane & 15);
        float v = acc[fr][fc][r] + bias[gcol];
        if (!ok) v = X[(size_t)grow * D + gcol];
        C[(size_t)grow * D + gcol] = v;
      }
    }
  }
}

// ---------------------------------------------------------------------------
// Kernel 3: gathered 16-neighbor attention, bf16 K/V/Q, fp32 accumulate.
// One wave per (b,l); 4 waves/block. h = lane>>3; phase1 n = (lane&7)+8t.
// ---------------------------------------------------------------------------
__global__ __launch_bounds__(256) void attn_kernel(const ushort* __restrict__ qb,
                                                   const ushort* __restrict__ kb,
                                                   const ushort* __restrict__ vb,
                                                   const int* __restrict__ nbr,
                                                   ushort* __restrict__ ctx) {
  __shared__ float sc[4][NH][KN];
  const int wave = threadIdx.x >> 6;
  const int lane = threadIdx.x & 63;
  const int bl = blockIdx.x * 4 + wave;
  const int bbase = (bl >> 12) << 12;          // b * L
  const int* nb = nbr + (size_t)bl * KN;

  const int h = lane >> 3;
  const int n0 = lane & 7;

  const ushort* qp = qb + (size_t)bl * D + h * DH;
  uint4 qv[8];
#pragma unroll
  for (int i = 0; i < 8; ++i)
    qv[i] = *reinterpret_cast<const uint4*>(qp + i * 8);

#pragma unroll
  for (int t = 0; t < 2; ++t) {
    const int j = nb[n0 + t * 8];
    const ushort* kr = kb + (size_t)(bbase + j) * D + h * DH;
    float a = 0.f;
#pragma unroll
    for (int i = 0; i < 8; ++i)
      a = dot8(qv[i], *reinterpret_cast<const uint4*>(kr + i * 8), a);
    sc[wave][h][n0 + t * 8] = a;
  }
  __syncthreads();

  float e[KN];
  float mx = -FLT_MAX;
#pragma unroll
  for (int n = 0; n < KN; ++n) mx = fmaxf(mx, sc[wave][h][n]);
  float sum = 0.f;
#pragma unroll
  for (int n = 0; n < KN; ++n) { e[n] = expf(sc[wave][h][n] - mx); sum += e[n]; }
  const float inv = 1.0f / sum;

  const int d0 = (lane & 7) * 8;
  float acc[8];
#pragma unroll
  for (int i = 0; i < 8; ++i) acc[i] = 0.f;
#pragma unroll
  for (int n = 0; n < KN; ++n) {
    const int j = nb[n];
    const uint4 vv = *reinterpret_cast<const uint4*>(
        vb + (size_t)(bbase + j) * D + h * DH + d0);
    const float w = e[n] * inv;
    acc[0] = fmaf(w, bf2f((ushort)vv.x), acc[0]);
    acc[1] = fmaf(w, bf2f((ushort)(vv.x >> 16)), acc[1]);
    acc[2] = fmaf(w, bf2f((ushort)vv.y), acc[2]);
    acc[3] = fmaf(w, bf2f((ushort)(vv.y >> 16)), acc[3]);
    acc[4] = fmaf(w, bf2f((ushort)vv.z), acc[4]);
    acc[5] = fmaf(w, bf2f((ushort)(vv.z >> 16)), acc[5]);
    acc[6] = fmaf(w, bf2f((ushort)vv.w), acc[6]);
    acc[7] = fmaf(w, bf2f((ushort)(vv.w >> 16)), acc[7]);
  }
  uint4 o;
  o.x = (unsigned)f2bf(acc[0]) | ((unsigned)f2bf(acc[1]) << 16);
  o.y = (unsigned)f2bf(acc[2]) | ((unsigned)f2bf(acc[3]) << 16);
  o.z = (unsigned)f2bf(acc[4]) | ((unsigned)f2bf(acc[5]) << 16);
  o.w = (unsigned)f2bf(acc[6]) | ((unsigned)f2bf(acc[7]) << 16);
  *reinterpret_cast<uint4*>(ctx + (size_t)bl * D + h * DH + d0) = o;
}

// ---------------------------------------------------------------------------
extern "C" void kernel_launch(void* const* d_in, const int* in_sizes, int n_in,
                              void* d_out, int out_size, void* d_ws, size_t ws_size,
                              hipStream_t stream) {
  const float* x     = (const float*)d_in[0];
  const float* pos   = (const float*)d_in[1];
  const float* in_w  = (const float*)d_in[2];
  const float* in_b  = (const float*)d_in[3];
  const float* out_w = (const float*)d_in[4];
  const float* out_b = (const float*)d_in[5];
  float* out = (float*)d_out;

  const size_t nbr_bytes  = (size_t)M * KN * sizeof(int);   // 1 MB
  const size_t isin_bytes = (size_t)M * sizeof(int);        // 64 KB
  const size_t half_bytes = (size_t)M * D * sizeof(ushort); // 16.8 MB each
  const size_t need = nbr_bytes + isin_bytes + 4 * half_bytes + 4096;
  if (ws_size < need) return;

  char* w = (char*)d_ws;
  int*    nbr  = (int*)w;    w += (nbr_bytes + 255) & ~(size_t)255;
  int*    isin = (int*)w;    w += (isin_bytes + 255) & ~(size_t)255;
  ushort* qb   = (ushort*)w; w += (half_bytes + 255) & ~(size_t)255;
  ushort* kb   = (ushort*)w; w += (half_bytes + 255) & ~(size_t)255;
  ushort* vb   = (ushort*)w; w += (half_bytes + 255) & ~(size_t)255;
  ushort* ctxb = (ushort*)w;

  // 1) top-k neighbors: one wave/query, 8 waves/block, threshold-pruned
  topk_kernel<<<B * (L / 8), 512, 0, stream>>>(pos, nbr, isin);

  // 2) in_proj -> bf16 Q(scaled)/K/V
  gemm_in<<<dim3(M / BM, N_IN / BN), 256, 0, stream>>>(x, in_w, in_b, qb, kb, vb);

  // 3) gathered neighbor attention -> bf16 ctx
  attn_kernel<<<M / 4, 256, 0, stream>>>(qb, kb, vb, nbr, ctxb);

  // 4) out_proj (A bf16 direct, W hi/lo 2-pass) + isin select
  gemm_out<<<dim3(M / BM, D / BN), 256, 0, stream>>>(ctxb, out_w, out_b, out, x, isin);
}

// Round 7
// 210.191 us; speedup vs baseline: 7.5454x; 1.2975x over previous
//
#include <hip/hip_runtime.h>
#include <cfloat>
#include <cmath>

constexpr int B = 4;
constexpr int L = 4096;
constexpr int D = 512;
constexpr int NH = 8;
constexpr int DH = 64;
constexpr int KN = 16;
constexpr int M = B * L;          // 16384 rows
constexpr int N_IN = 3 * D;       // 1536

typedef __attribute__((ext_vector_type(8))) short short8;   // 8 bf16 = 4 VGPR
typedef __attribute__((ext_vector_type(4))) float f32x4;    // MFMA acc
typedef unsigned short ushort;

__device__ __forceinline__ ushort f2bf(float f) {   // RN-even bf16
  unsigned u = __float_as_uint(f);
  u = u + 0x7fffu + ((u >> 16) & 1u);
  return (ushort)(u >> 16);
}
__device__ __forceinline__ float bf2f(ushort h) {
  return __uint_as_float(((unsigned)h) << 16);
}
__device__ __forceinline__ float dot8(const uint4 qu, const uint4 ku, float a) {
  a = fmaf(bf2f((ushort)qu.x), bf2f((ushort)ku.x), a);
  a = fmaf(bf2f((ushort)(qu.x >> 16)), bf2f((ushort)(ku.x >> 16)), a);
  a = fmaf(bf2f((ushort)qu.y), bf2f((ushort)ku.y), a);
  a = fmaf(bf2f((ushort)(qu.y >> 16)), bf2f((ushort)(ku.y >> 16)), a);
  a = fmaf(bf2f((ushort)qu.z), bf2f((ushort)ku.z), a);
  a = fmaf(bf2f((ushort)(qu.z >> 16)), bf2f((ushort)(ku.z >> 16)), a);
  a = fmaf(bf2f((ushort)qu.w), bf2f((ushort)ku.w), a);
  a = fmaf(bf2f((ushort)(qu.w >> 16)), bf2f((ushort)(ku.w >> 16)), a);
  return a;
}

// ---------------------------------------------------------------------------
// Kernel 1: top-16 NN v3 (R6 structure, R7 fixes the lane-63 prefix mask).
// One wave/query, 8 waves/block. Positions in LDS transposed-padded:
// sT[c&63][c>>6], row stride 65 (65%32==1): phase A (lane l reads sT[l][j])
// banks (l+j)%32 -> 2-way alias, free; phase B (uniform row p, lane j reads
// sT[p][j]) stride-1 conflict-free.
// Phase A: per-lane min SQUARED dist (no sqrt). Threshold P via wave-uniform
// binary search on d2 bits (+16 ulp margin -> survivor set provably contains
// the exact top-16 under (sqrt,idx) order). Phase B: scalar loop over passing
// lanes (~18); all 64 lanes test that lane's candidates; survivors appended
// via ballot+prefix (below = (1<<lane)-1: bits strictly below, ALL lanes).
// sqrtf only for survivors -> exact (sqrt_bits<<32|idx) rank keys.
// ---------------------------------------------------------------------------
constexpr int TP = 65;   // padded row stride (words), 65 % 32 == 1

__global__ __launch_bounds__(512) void topk_kernel(const float* __restrict__ pos,
                                                   int* __restrict__ nbr,
                                                   int* __restrict__ isin) {
  __shared__ float sxT[64 * TP], syT[64 * TP], szT[64 * TP];  // 49.9 KB
  __shared__ unsigned long long lst[8 * 64];                  // 4 KB
  const int wave = threadIdx.x >> 6;
  const int lane = threadIdx.x & 63;
  const int b = blockIdx.x >> 9;              // 512 blocks per batch
  const int l = (blockIdx.x & 511) * 8 + wave;
  const int row = b * L + l;

  const float* p = pos + (size_t)b * L * 3;
  for (int i = threadIdx.x; i < L; i += 512) {
    const int a = (i & 63) * TP + (i >> 6);
    sxT[a] = p[3 * i + 0];
    syT[a] = p[3 * i + 1];
    szT[a] = p[3 * i + 2];
  }
  __syncthreads();

  const int qa = (l & 63) * TP + (l >> 6);
  const float qx = sxT[qa], qy = syT[qa], qz = szT[qa];

  // phase A: per-lane min squared distance, 4 independent accumulators
  float mA = FLT_MAX, mB2 = FLT_MAX, mC = FLT_MAX, mD2 = FLT_MAX;
  const int base = lane * TP;
  for (int j = 0; j < 64; j += 4) {
#define D2(t, acc)                                                   \
    {                                                                \
      const int a = base + j + t;                                    \
      const float dx = qx - sxT[a], dy = qy - syT[a], dz = qz - szT[a]; \
      acc = fminf(acc, fmaf(dx, dx, fmaf(dy, dy, dz * dz)));         \
    }
    D2(0, mA) D2(1, mB2) D2(2, mC) D2(3, mD2)
#undef D2
  }
  const unsigned mbits = __float_as_uint(fminf(fminf(mA, mB2), fminf(mC, mD2)));

  // smallest P with |{lane-min d2 bits < P}| >= 16, then +16 ulp margin
  unsigned lo = 1, hi = 0x40400001u;           // d2 <= 3.0
  while (lo < hi) {
    const unsigned mid = (lo + hi) >> 1;
    const int c = __popcll(__ballot(mbits < mid));
    if (c >= 16) hi = mid; else lo = mid + 1;
  }
  const unsigned P = lo + 16;                   // margin for sqrt-tie safety

  // phase B: cooperative re-scan of passing lanes' candidate rows
  int cnt = 0;                                  // wave-uniform
  unsigned long long am = __ballot(mbits < P);
  const unsigned long long below = (1ull << lane) - 1ull;  // bits strictly below
  while (am) {
    const int pl = (int)__builtin_ctzll(am);    // passing lane (uniform)
    am &= am - 1;
    const int a = pl * TP + lane;               // candidate c = lane*64 + pl
    const float dx = qx - sxT[a], dy = qy - syT[a], dz = qz - szT[a];
    const float d2 = fmaf(dx, dx, fmaf(dy, dy, dz * dz));
    const bool hit = __float_as_uint(d2) < P;
    const unsigned long long msk = __ballot(hit);
    if (hit) {
      const int slot = cnt + __popcll(msk & below);
      if (slot < 64) {
        const unsigned c = (unsigned)(lane * 64 + pl);
        lst[wave * 64 + slot] =
            ((unsigned long long)__float_as_uint(sqrtf(d2)) << 32) | c;
      }
    }
    cnt += __popcll(msk);
  }
  const int n = min(cnt, 64);                   // n >= 16 guaranteed

  // exact rank among survivors: (sqrt_bits asc, idx asc) == lax.top_k order
  const unsigned long long mine = (lane < n) ? lst[wave * 64 + lane] : ~0ull;
  int r = 0;
  for (int i = 0; i < n; ++i) r += (lst[wave * 64 + i] < mine) ? 1 : 0;

  const int idx = (int)(unsigned)(mine & 0xffffffffu);
  const bool wr = (lane < n) && (r < 16);
  if (wr) nbr[(size_t)row * KN + r] = idx;
  const unsigned long long hit2 = __ballot(wr && idx == l);
  if (lane == 0) isin[row] = hit2 ? 1 : 0;
}

// ---------------------------------------------------------------------------
// GEMM tiles: 128x128, BK=32, 4 waves (2x2 of 64x64), 16x16x32 bf16 MFMA.
// C/D layout col=lane&15, row=(lane>>4)*4+r  [m89-verified]
// ---------------------------------------------------------------------------
constexpr int BM = 128, BN = 128, BK = 32;
constexpr int LDT = 40;   // padded LDS row (80B stride -> 2-way alias, free)

// Kernel 2a: in_proj. A,W fp32 -> plain bf16 MFMA; epilogue writes bf16 into
// split Q (pre-scaled by 0.125), K, V buffers [M][512].
__global__ __launch_bounds__(256) void gemm_in(const float* __restrict__ A,
                                               const float* __restrict__ W,
                                               const float* __restrict__ bias,
                                               ushort* __restrict__ qb,
                                               ushort* __restrict__ kb,
                                               ushort* __restrict__ vb) {
  __shared__ ushort Ah[BM][LDT];
  __shared__ ushort Bh[BN][LDT];

  const int tid = threadIdx.x;
  const int m0 = blockIdx.x * BM;
  const int n0 = blockIdx.y * BN;

  const int srow = tid >> 1;
  const int scol = (tid & 1) * 16;
  const float* Aptr = A + (size_t)(m0 + srow) * D + scol;
  const float* Wptr = W + (size_t)(n0 + srow) * D + scol;

  const int wave = tid >> 6;
  const int lane = tid & 63;
  const int wr0 = (wave >> 1) * 64;
  const int wc0 = (wave & 1) * 64;
  const int fr_row = lane & 15;
  const int kof = (lane >> 4) * 8;

  f32x4 acc[4][4];
#pragma unroll
  for (int i = 0; i < 4; ++i)
#pragma unroll
    for (int j = 0; j < 4; ++j) acc[i][j] = {0.f, 0.f, 0.f, 0.f};

  for (int k0 = 0; k0 < D; k0 += BK) {
    __syncthreads();
#pragma unroll
    for (int j = 0; j < 4; ++j) {
      const int c = scol + j * 4;
      {
        const float4 v = *reinterpret_cast<const float4*>(Aptr + k0 + j * 4);
        uint2 hp;
        hp.x = (unsigned)f2bf(v.x) | ((unsigned)f2bf(v.y) << 16);
        hp.y = (unsigned)f2bf(v.z) | ((unsigned)f2bf(v.w) << 16);
        *reinterpret_cast<uint2*>(&Ah[srow][c]) = hp;
      }
      {
        const float4 v = *reinterpret_cast<const float4*>(Wptr + k0 + j * 4);
        uint2 hp;
        hp.x = (unsigned)f2bf(v.x) | ((unsigned)f2bf(v.y) << 16);
        hp.y = (unsigned)f2bf(v.z) | ((unsigned)f2bf(v.w) << 16);
        *reinterpret_cast<uint2*>(&Bh[srow][c]) = hp;
      }
    }
    __syncthreads();

    short8 ah[4];
#pragma unroll
    for (int fr = 0; fr < 4; ++fr)
      ah[fr] = *reinterpret_cast<const short8*>(&Ah[wr0 + fr * 16 + fr_row][kof]);
#pragma unroll
    for (int fc = 0; fc < 4; ++fc) {
      const short8 bh = *reinterpret_cast<const short8*>(&Bh[wc0 + fc * 16 + fr_row][kof]);
#pragma unroll
      for (int fr = 0; fr < 4; ++fr)
        acc[fr][fc] = __builtin_amdgcn_mfma_f32_16x16x32_bf16(ah[fr], bh, acc[fr][fc], 0, 0, 0);
    }
  }

  const int region = n0 >> 9;             // 0=q, 1=k, 2=v (BN=128 stays inside)
  ushort* outb = region == 0 ? qb : (region == 1 ? kb : vb);
  const float scl = region == 0 ? 0.125f : 1.0f;
  const int nloc0 = (n0 & 511) + wc0;
#pragma unroll
  for (int fr = 0; fr < 4; ++fr) {
#pragma unroll
    for (int r = 0; r < 4; ++r) {
      const int grow = m0 + wr0 + fr * 16 + (lane >> 4) * 4 + r;
#pragma unroll
      for (int fc = 0; fc < 4; ++fc) {
        const int cc = fc * 16 + (lane & 15);
        const float v = (acc[fr][fc][r] + bias[n0 + wc0 + cc]) * scl;
        outb[(size_t)grow * D + nloc0 + cc] = f2bf(v);
      }
    }
  }
}

// Kernel 2b: out_proj. A = ctx (bf16, staged directly), W fp32 split hi/lo
// (2 MFMA chains -> ~fp32 accuracy). Epilogue: isin-select vs X, fp32 out.
__global__ __launch_bounds__(256) void gemm_out(const ushort* __restrict__ A,
                                                const float* __restrict__ W,
                                                const float* __restrict__ bias,
                                                float* __restrict__ C,
                                                const float* __restrict__ X,
                                                const int* __restrict__ isin) {
  __shared__ ushort Ah[BM][LDT];
  __shared__ ushort Bh[BN][LDT];
  __shared__ ushort Bl[BN][LDT];

  const int tid = threadIdx.x;
  const int m0 = blockIdx.x * BM;
  const int n0 = blockIdx.y * BN;

  const int srow = tid >> 1;
  const int scol = (tid & 1) * 16;
  const ushort* Aptr = A + (size_t)(m0 + srow) * D + scol;
  const float* Wptr = W + (size_t)(n0 + srow) * D + scol;

  const int wave = tid >> 6;
  const int lane = tid & 63;
  const int wr0 = (wave >> 1) * 64;
  const int wc0 = (wave & 1) * 64;
  const int fr_row = lane & 15;
  const int kof = (lane >> 4) * 8;

  f32x4 acc[4][4];
#pragma unroll
  for (int i = 0; i < 4; ++i)
#pragma unroll
    for (int j = 0; j < 4; ++j) acc[i][j] = {0.f, 0.f, 0.f, 0.f};

  for (int k0 = 0; k0 < D; k0 += BK) {
    __syncthreads();
    {
      const uint4* s = reinterpret_cast<const uint4*>(Aptr + k0);
      *reinterpret_cast<uint4*>(&Ah[srow][scol]) = s[0];
      *reinterpret_cast<uint4*>(&Ah[srow][scol + 8]) = s[1];
    }
#pragma unroll
    for (int j = 0; j < 4; ++j) {
      const int c = scol + j * 4;
      const float4 v = *reinterpret_cast<const float4*>(Wptr + k0 + j * 4);
      const ushort h0 = f2bf(v.x), h1 = f2bf(v.y), h2 = f2bf(v.z), h3 = f2bf(v.w);
      uint2 hp, lp;
      hp.x = (unsigned)h0 | ((unsigned)h1 << 16);
      hp.y = (unsigned)h2 | ((unsigned)h3 << 16);
      lp.x = (unsigned)f2bf(v.x - bf2f(h0)) | ((unsigned)f2bf(v.y - bf2f(h1)) << 16);
      lp.y = (unsigned)f2bf(v.z - bf2f(h2)) | ((unsigned)f2bf(v.w - bf2f(h3)) << 16);
      *reinterpret_cast<uint2*>(&Bh[srow][c]) = hp;
      *reinterpret_cast<uint2*>(&Bl[srow][c]) = lp;
    }
    __syncthreads();

    short8 ah[4];
#pragma unroll
    for (int fr = 0; fr < 4; ++fr)
      ah[fr] = *reinterpret_cast<const short8*>(&Ah[wr0 + fr * 16 + fr_row][kof]);
#pragma unroll
    for (int fc = 0; fc < 4; ++fc) {
      const short8 bh = *reinterpret_cast<const short8*>(&Bh[wc0 + fc * 16 + fr_row][kof]);
      const short8 bl = *reinterpret_cast<const short8*>(&Bl[wc0 + fc * 16 + fr_row][kof]);
#pragma unroll
      for (int fr = 0; fr < 4; ++fr) {
        acc[fr][fc] = __builtin_amdgcn_mfma_f32_16x16x32_bf16(ah[fr], bh, acc[fr][fc], 0, 0, 0);
        acc[fr][fc] = __builtin_amdgcn_mfma_f32_16x16x32_bf16(ah[fr], bl, acc[fr][fc], 0, 0, 0);
      }
    }
  }

#pragma unroll
  for (int fr = 0; fr < 4; ++fr) {
#pragma unroll
    for (int r = 0; r < 4; ++r) {
      const int grow = m0 + wr0 + fr * 16 + (lane >> 4) * 4 + r;
      const int ok = isin[grow];
#pragma unroll
      for (int fc = 0; fc < 4; ++fc) {
        const int gcol = n0 + wc0 + fc * 16 + (lane & 15);
        float v = acc[fr][fc][r] + bias[gcol];
        if (!ok) v = X[(size_t)grow * D + gcol];
        C[(size_t)grow * D + gcol] = v;
      }
    }
  }
}

// ---------------------------------------------------------------------------
// Kernel 3: gathered 16-neighbor attention, bf16 K/V/Q, fp32 accumulate.
// One wave per (b,l); 4 waves/block. h = lane>>3; phase1 n = (lane&7)+8t.
// ---------------------------------------------------------------------------
__global__ __launch_bounds__(256) void attn_kernel(const ushort* __restrict__ qb,
                                                   const ushort* __restrict__ kb,
                                                   const ushort* __restrict__ vb,
                                                   const int* __restrict__ nbr,
                                                   ushort* __restrict__ ctx) {
  __shared__ float sc[4][NH][KN];
  const int wave = threadIdx.x >> 6;
  const int lane = threadIdx.x & 63;
  const int bl = blockIdx.x * 4 + wave;
  const int bbase = (bl >> 12) << 12;          // b * L
  const int* nb = nbr + (size_t)bl * KN;

  const int h = lane >> 3;
  const int n0 = lane & 7;

  const ushort* qp = qb + (size_t)bl * D + h * DH;
  uint4 qv[8];
#pragma unroll
  for (int i = 0; i < 8; ++i)
    qv[i] = *reinterpret_cast<const uint4*>(qp + i * 8);

#pragma unroll
  for (int t = 0; t < 2; ++t) {
    const int j = nb[n0 + t * 8];
    const ushort* kr = kb + (size_t)(bbase + j) * D + h * DH;
    float a = 0.f;
#pragma unroll
    for (int i = 0; i < 8; ++i)
      a = dot8(qv[i], *reinterpret_cast<const uint4*>(kr + i * 8), a);
    sc[wave][h][n0 + t * 8] = a;
  }
  __syncthreads();

  float e[KN];
  float mx = -FLT_MAX;
#pragma unroll
  for (int n = 0; n < KN; ++n) mx = fmaxf(mx, sc[wave][h][n]);
  float sum = 0.f;
#pragma unroll
  for (int n = 0; n < KN; ++n) { e[n] = expf(sc[wave][h][n] - mx); sum += e[n]; }
  const float inv = 1.0f / sum;

  const int d0 = (lane & 7) * 8;
  float acc[8];
#pragma unroll
  for (int i = 0; i < 8; ++i) acc[i] = 0.f;
#pragma unroll
  for (int n = 0; n < KN; ++n) {
    const int j = nb[n];
    const uint4 vv = *reinterpret_cast<const uint4*>(
        vb + (size_t)(bbase + j) * D + h * DH + d0);
    const float w = e[n] * inv;
    acc[0] = fmaf(w, bf2f((ushort)vv.x), acc[0]);
    acc[1] = fmaf(w, bf2f((ushort)(vv.x >> 16)), acc[1]);
    acc[2] = fmaf(w, bf2f((ushort)vv.y), acc[2]);
    acc[3] = fmaf(w, bf2f((ushort)(vv.y >> 16)), acc[3]);
    acc[4] = fmaf(w, bf2f((ushort)vv.z), acc[4]);
    acc[5] = fmaf(w, bf2f((ushort)(vv.z >> 16)), acc[5]);
    acc[6] = fmaf(w, bf2f((ushort)vv.w), acc[6]);
    acc[7] = fmaf(w, bf2f((ushort)(vv.w >> 16)), acc[7]);
  }
  uint4 o;
  o.x = (unsigned)f2bf(acc[0]) | ((unsigned)f2bf(acc[1]) << 16);
  o.y = (unsigned)f2bf(acc[2]) | ((unsigned)f2bf(acc[3]) << 16);
  o.z = (unsigned)f2bf(acc[4]) | ((unsigned)f2bf(acc[5]) << 16);
  o.w = (unsigned)f2bf(acc[6]) | ((unsigned)f2bf(acc[7]) << 16);
  *reinterpret_cast<uint4*>(ctx + (size_t)bl * D + h * DH + d0) = o;
}

// ---------------------------------------------------------------------------
extern "C" void kernel_launch(void* const* d_in, const int* in_sizes, int n_in,
                              void* d_out, int out_size, void* d_ws, size_t ws_size,
                              hipStream_t stream) {
  const float* x     = (const float*)d_in[0];
  const float* pos   = (const float*)d_in[1];
  const float* in_w  = (const float*)d_in[2];
  const float* in_b  = (const float*)d_in[3];
  const float* out_w = (const float*)d_in[4];
  const float* out_b = (const float*)d_in[5];
  float* out = (float*)d_out;

  const size_t nbr_bytes  = (size_t)M * KN * sizeof(int);   // 1 MB
  const size_t isin_bytes = (size_t)M * sizeof(int);        // 64 KB
  const size_t half_bytes = (size_t)M * D * sizeof(ushort); // 16.8 MB each
  const size_t need = nbr_bytes + isin_bytes + 4 * half_bytes + 4096;
  if (ws_size < need) return;

  char* w = (char*)d_ws;
  int*    nbr  = (int*)w;    w += (nbr_bytes + 255) & ~(size_t)255;
  int*    isin = (int*)w;    w += (isin_bytes + 255) & ~(size_t)255;
  ushort* qb   = (ushort*)w; w += (half_bytes + 255) & ~(size_t)255;
  ushort* kb   = (ushort*)w; w += (half_bytes + 255) & ~(size_t)255;
  ushort* vb   = (ushort*)w; w += (half_bytes + 255) & ~(size_t)255;
  ushort* ctxb = (ushort*)w;

  // 1) top-k neighbors: one wave/query, 8 waves/block, cooperative phase B
  topk_kernel<<<B * (L / 8), 512, 0, stream>>>(pos, nbr, isin);

  // 2) in_proj -> bf16 Q(scaled)/K/V
  gemm_in<<<dim3(M / BM, N_IN / BN), 256, 0, stream>>>(x, in_w, in_b, qb, kb, vb);

  // 3) gathered neighbor attention -> bf16 ctx
  attn_kernel<<<M / 4, 256, 0, stream>>>(qb, kb, vb, nbr, ctxb);

  // 4) out_proj (A bf16 direct, W hi/lo 2-pass) + isin select
  gemm_out<<<dim3(M / BM, D / BN), 256, 0, stream>>>(ctxb, out_w, out_b, out, x, isin);
}

// Round 8
// 191.022 us; speedup vs baseline: 8.3026x; 1.1003x over previous
//
#include <hip/hip_runtime.h>
#include <cfloat>
#include <cmath>

constexpr int B = 4;
constexpr int L = 4096;
constexpr int D = 512;
constexpr int NH = 8;
constexpr int DH = 64;
constexpr int KN = 16;
constexpr int M = B * L;          // 16384 rows
constexpr int N_IN = 3 * D;       // 1536

typedef __attribute__((ext_vector_type(8))) short short8;   // 8 bf16 = 4 VGPR
typedef __attribute__((ext_vector_type(4))) float f32x4;    // MFMA acc
typedef unsigned short ushort;

__device__ __forceinline__ ushort f2bf(float f) {   // RN-even bf16
  unsigned u = __float_as_uint(f);
  u = u + 0x7fffu + ((u >> 16) & 1u);
  return (ushort)(u >> 16);
}
__device__ __forceinline__ float bf2f(ushort h) {
  return __uint_as_float(((unsigned)h) << 16);
}
__device__ __forceinline__ float dot8(const uint4 qu, const uint4 ku, float a) {
  a = fmaf(bf2f((ushort)qu.x), bf2f((ushort)ku.x), a);
  a = fmaf(bf2f((ushort)(qu.x >> 16)), bf2f((ushort)(ku.x >> 16)), a);
  a = fmaf(bf2f((ushort)qu.y), bf2f((ushort)ku.y), a);
  a = fmaf(bf2f((ushort)(qu.y >> 16)), bf2f((ushort)(ku.y >> 16)), a);
  a = fmaf(bf2f((ushort)qu.z), bf2f((ushort)ku.z), a);
  a = fmaf(bf2f((ushort)(qu.z >> 16)), bf2f((ushort)(ku.z >> 16)), a);
  a = fmaf(bf2f((ushort)qu.w), bf2f((ushort)ku.w), a);
  a = fmaf(bf2f((ushort)(qu.w >> 16)), bf2f((ushort)(ku.w >> 16)), a);
  return a;
}
__device__ __forceinline__ uint2 pack4hi(const float4 v) {
  uint2 o;
  o.x = (unsigned)f2bf(v.x) | ((unsigned)f2bf(v.y) << 16);
  o.y = (unsigned)f2bf(v.z) | ((unsigned)f2bf(v.w) << 16);
  return o;
}

// ---------------------------------------------------------------------------
// Kernel 0a: x (fp32) -> xb (bf16). Memory-bound, 8 elems/thread/iter.
// ---------------------------------------------------------------------------
__global__ __launch_bounds__(256) void cvt_x_kernel(const float* __restrict__ in,
                                                    ushort* __restrict__ out) {
  const int n8 = M * D / 8;
  for (int i = blockIdx.x * 256 + threadIdx.x; i < n8; i += gridDim.x * 256) {
    const float4 v0 = reinterpret_cast<const float4*>(in)[i * 2];
    const float4 v1 = reinterpret_cast<const float4*>(in)[i * 2 + 1];
    uint4 o;
    const uint2 a = pack4hi(v0), b2 = pack4hi(v1);
    o.x = a.x; o.y = a.y; o.z = b2.x; o.w = b2.y;
    reinterpret_cast<uint4*>(out)[i] = o;
  }
}

// ---------------------------------------------------------------------------
// Kernel 0b: in_w -> iwh (bf16 hi); out_w -> owh + owl (bf16 hi/lo split).
// ---------------------------------------------------------------------------
__global__ __launch_bounds__(256) void cvt_w_kernel(const float* __restrict__ in_w,
                                                    const float* __restrict__ out_w,
                                                    ushort* __restrict__ iwh,
                                                    ushort* __restrict__ owh,
                                                    ushort* __restrict__ owl) {
  const int ni8 = N_IN * D / 8;   // 98304
  const int no8 = D * D / 8;      // 32768
  for (int i = blockIdx.x * 256 + threadIdx.x; i < ni8 + no8; i += gridDim.x * 256) {
    if (i < ni8) {
      const float4 v0 = reinterpret_cast<const float4*>(in_w)[i * 2];
      const float4 v1 = reinterpret_cast<const float4*>(in_w)[i * 2 + 1];
      uint4 o;
      const uint2 a = pack4hi(v0), b2 = pack4hi(v1);
      o.x = a.x; o.y = a.y; o.z = b2.x; o.w = b2.y;
      reinterpret_cast<uint4*>(iwh)[i] = o;
    } else {
      const int j = i - ni8;
      const float4 v0 = reinterpret_cast<const float4*>(out_w)[j * 2];
      const float4 v1 = reinterpret_cast<const float4*>(out_w)[j * 2 + 1];
      uint4 oh, ol;
      const uint2 a = pack4hi(v0), b2 = pack4hi(v1);
      oh.x = a.x; oh.y = a.y; oh.z = b2.x; oh.w = b2.y;
      const float4 r0 = make_float4(v0.x - bf2f(f2bf(v0.x)), v0.y - bf2f(f2bf(v0.y)),
                                    v0.z - bf2f(f2bf(v0.z)), v0.w - bf2f(f2bf(v0.w)));
      const float4 r1 = make_float4(v1.x - bf2f(f2bf(v1.x)), v1.y - bf2f(f2bf(v1.y)),
                                    v1.z - bf2f(f2bf(v1.z)), v1.w - bf2f(f2bf(v1.w)));
      const uint2 c = pack4hi(r0), d2 = pack4hi(r1);
      ol.x = c.x; ol.y = c.y; ol.z = d2.x; ol.w = d2.y;
      reinterpret_cast<uint4*>(owh)[j] = oh;
      reinterpret_cast<uint4*>(owl)[j] = ol;
    }
  }
}

// ---------------------------------------------------------------------------
// Kernel 1: top-16 NN (unchanged from R7).
// ---------------------------------------------------------------------------
constexpr int TP = 65;   // padded row stride (words), 65 % 32 == 1

__global__ __launch_bounds__(512) void topk_kernel(const float* __restrict__ pos,
                                                   int* __restrict__ nbr,
                                                   int* __restrict__ isin) {
  __shared__ float sxT[64 * TP], syT[64 * TP], szT[64 * TP];  // 49.9 KB
  __shared__ unsigned long long lst[8 * 64];                  // 4 KB
  const int wave = threadIdx.x >> 6;
  const int lane = threadIdx.x & 63;
  const int b = blockIdx.x >> 9;
  const int l = (blockIdx.x & 511) * 8 + wave;
  const int row = b * L + l;

  const float* p = pos + (size_t)b * L * 3;
  for (int i = threadIdx.x; i < L; i += 512) {
    const int a = (i & 63) * TP + (i >> 6);
    sxT[a] = p[3 * i + 0];
    syT[a] = p[3 * i + 1];
    szT[a] = p[3 * i + 2];
  }
  __syncthreads();

  const int qa = (l & 63) * TP + (l >> 6);
  const float qx = sxT[qa], qy = syT[qa], qz = szT[qa];

  float mA = FLT_MAX, mB2 = FLT_MAX, mC = FLT_MAX, mD2 = FLT_MAX;
  const int base = lane * TP;
  for (int j = 0; j < 64; j += 4) {
#define D2(t, acc)                                                   \
    {                                                                \
      const int a = base + j + t;                                    \
      const float dx = qx - sxT[a], dy = qy - syT[a], dz = qz - szT[a]; \
      acc = fminf(acc, fmaf(dx, dx, fmaf(dy, dy, dz * dz)));         \
    }
    D2(0, mA) D2(1, mB2) D2(2, mC) D2(3, mD2)
#undef D2
  }
  const unsigned mbits = __float_as_uint(fminf(fminf(mA, mB2), fminf(mC, mD2)));

  unsigned lo = 1, hi = 0x40400001u;
  while (lo < hi) {
    const unsigned mid = (lo + hi) >> 1;
    const int c = __popcll(__ballot(mbits < mid));
    if (c >= 16) hi = mid; else lo = mid + 1;
  }
  const unsigned P = lo + 16;

  int cnt = 0;
  unsigned long long am = __ballot(mbits < P);
  const unsigned long long below = (1ull << lane) - 1ull;
  while (am) {
    const int pl = (int)__builtin_ctzll(am);
    am &= am - 1;
    const int a = pl * TP + lane;
    const float dx = qx - sxT[a], dy = qy - syT[a], dz = qz - szT[a];
    const float d2 = fmaf(dx, dx, fmaf(dy, dy, dz * dz));
    const bool hit = __float_as_uint(d2) < P;
    const unsigned long long msk = __ballot(hit);
    if (hit) {
      const int slot = cnt + __popcll(msk & below);
      if (slot < 64) {
        const unsigned c = (unsigned)(lane * 64 + pl);
        lst[wave * 64 + slot] =
            ((unsigned long long)__float_as_uint(sqrtf(d2)) << 32) | c;
      }
    }
    cnt += __popcll(msk);
  }
  const int n = min(cnt, 64);

  const unsigned long long mine = (lane < n) ? lst[wave * 64 + lane] : ~0ull;
  int r = 0;
  for (int i = 0; i < n; ++i) r += (lst[wave * 64 + i] < mine) ? 1 : 0;

  const int idx = (int)(unsigned)(mine & 0xffffffffu);
  const bool wr = (lane < n) && (r < 16);
  if (wr) nbr[(size_t)row * KN + r] = idx;
  const unsigned long long hit2 = __ballot(wr && idx == l);
  if (lane == 0) isin[row] = hit2 ? 1 : 0;
}

// ---------------------------------------------------------------------------
// GEMM tiles: 128x128, BK=32, 4 waves (2x2 of 64x64), 16x16x32 bf16 MFMA.
// All inputs pre-converted bf16 -> staging is straight uint4 copies.
// C/D layout col=lane&15, row=(lane>>4)*4+r  [m89-verified]
// ---------------------------------------------------------------------------
constexpr int BM = 128, BN = 128, BK = 32;
constexpr int LDT = 40;   // padded row (80B stride): 2-way alias on b128 reads

// Kernel 2a: in_proj (bf16 x bf16). Epilogue -> bf16 Q(scaled)/K/V.
__global__ __launch_bounds__(256) void gemm_in(const ushort* __restrict__ A,
                                               const ushort* __restrict__ W,
                                               const float* __restrict__ bias,
                                               ushort* __restrict__ qb,
                                               ushort* __restrict__ kb,
                                               ushort* __restrict__ vb) {
  __shared__ ushort Ah[BM][LDT];
  __shared__ ushort Bh[BN][LDT];

  const int tid = threadIdx.x;
  const int m0 = blockIdx.x * BM;
  const int n0 = blockIdx.y * BN;

  const int srow = tid >> 1;
  const int scol = (tid & 1) * 16;
  const ushort* Aptr = A + (size_t)(m0 + srow) * D + scol;
  const ushort* Wptr = W + (size_t)(n0 + srow) * D + scol;

  const int wave = tid >> 6;
  const int lane = tid & 63;
  const int wr0 = (wave >> 1) * 64;
  const int wc0 = (wave & 1) * 64;
  const int fr_row = lane & 15;
  const int kof = (lane >> 4) * 8;

  f32x4 acc[4][4];
#pragma unroll
  for (int i = 0; i < 4; ++i)
#pragma unroll
    for (int j = 0; j < 4; ++j) acc[i][j] = {0.f, 0.f, 0.f, 0.f};

  for (int k0 = 0; k0 < D; k0 += BK) {
    __syncthreads();
    {
      const uint4* as = reinterpret_cast<const uint4*>(Aptr + k0);
      *reinterpret_cast<uint4*>(&Ah[srow][scol]) = as[0];
      *reinterpret_cast<uint4*>(&Ah[srow][scol + 8]) = as[1];
      const uint4* ws = reinterpret_cast<const uint4*>(Wptr + k0);
      *reinterpret_cast<uint4*>(&Bh[srow][scol]) = ws[0];
      *reinterpret_cast<uint4*>(&Bh[srow][scol + 8]) = ws[1];
    }
    __syncthreads();

    short8 ah[4];
#pragma unroll
    for (int fr = 0; fr < 4; ++fr)
      ah[fr] = *reinterpret_cast<const short8*>(&Ah[wr0 + fr * 16 + fr_row][kof]);
#pragma unroll
    for (int fc = 0; fc < 4; ++fc) {
      const short8 bh = *reinterpret_cast<const short8*>(&Bh[wc0 + fc * 16 + fr_row][kof]);
#pragma unroll
      for (int fr = 0; fr < 4; ++fr)
        acc[fr][fc] = __builtin_amdgcn_mfma_f32_16x16x32_bf16(ah[fr], bh, acc[fr][fc], 0, 0, 0);
    }
  }

  const int region = n0 >> 9;             // 0=q, 1=k, 2=v
  ushort* outb = region == 0 ? qb : (region == 1 ? kb : vb);
  const float scl = region == 0 ? 0.125f : 1.0f;
  const int nloc0 = (n0 & 511) + wc0;
#pragma unroll
  for (int fr = 0; fr < 4; ++fr) {
#pragma unroll
    for (int r = 0; r < 4; ++r) {
      const int grow = m0 + wr0 + fr * 16 + (lane >> 4) * 4 + r;
#pragma unroll
      for (int fc = 0; fc < 4; ++fc) {
        const int cc = fc * 16 + (lane & 15);
        const float v = (acc[fr][fc][r] + bias[n0 + wc0 + cc]) * scl;
        outb[(size_t)grow * D + nloc0 + cc] = f2bf(v);
      }
    }
  }
}

// Kernel 2b: out_proj. A = ctx bf16; W = pre-split bf16 hi/lo (2 MFMA chains).
__global__ __launch_bounds__(256) void gemm_out(const ushort* __restrict__ A,
                                                const ushort* __restrict__ Wh,
                                                const ushort* __restrict__ Wl,
                                                const float* __restrict__ bias,
                                                float* __restrict__ C,
                                                const float* __restrict__ X,
                                                const int* __restrict__ isin) {
  __shared__ ushort Ah[BM][LDT];
  __shared__ ushort Bh[BN][LDT];
  __shared__ ushort Bl[BN][LDT];

  const int tid = threadIdx.x;
  const int m0 = blockIdx.x * BM;
  const int n0 = blockIdx.y * BN;

  const int srow = tid >> 1;
  const int scol = (tid & 1) * 16;
  const ushort* Aptr = A + (size_t)(m0 + srow) * D + scol;
  const ushort* Whp = Wh + (size_t)(n0 + srow) * D + scol;
  const ushort* Wlp = Wl + (size_t)(n0 + srow) * D + scol;

  const int wave = tid >> 6;
  const int lane = tid & 63;
  const int wr0 = (wave >> 1) * 64;
  const int wc0 = (wave & 1) * 64;
  const int fr_row = lane & 15;
  const int kof = (lane >> 4) * 8;

  f32x4 acc[4][4];
#pragma unroll
  for (int i = 0; i < 4; ++i)
#pragma unroll
    for (int j = 0; j < 4; ++j) acc[i][j] = {0.f, 0.f, 0.f, 0.f};

  for (int k0 = 0; k0 < D; k0 += BK) {
    __syncthreads();
    {
      const uint4* as = reinterpret_cast<const uint4*>(Aptr + k0);
      *reinterpret_cast<uint4*>(&Ah[srow][scol]) = as[0];
      *reinterpret_cast<uint4*>(&Ah[srow][scol + 8]) = as[1];
      const uint4* hs = reinterpret_cast<const uint4*>(Whp + k0);
      *reinterpret_cast<uint4*>(&Bh[srow][scol]) = hs[0];
      *reinterpret_cast<uint4*>(&Bh[srow][scol + 8]) = hs[1];
      const uint4* ls = reinterpret_cast<const uint4*>(Wlp + k0);
      *reinterpret_cast<uint4*>(&Bl[srow][scol]) = ls[0];
      *reinterpret_cast<uint4*>(&Bl[srow][scol + 8]) = ls[1];
    }
    __syncthreads();

    short8 ah[4];
#pragma unroll
    for (int fr = 0; fr < 4; ++fr)
      ah[fr] = *reinterpret_cast<const short8*>(&Ah[wr0 + fr * 16 + fr_row][kof]);
#pragma unroll
    for (int fc = 0; fc < 4; ++fc) {
      const short8 bh = *reinterpret_cast<const short8*>(&Bh[wc0 + fc * 16 + fr_row][kof]);
      const short8 bl = *reinterpret_cast<const short8*>(&Bl[wc0 + fc * 16 + fr_row][kof]);
#pragma unroll
      for (int fr = 0; fr < 4; ++fr) {
        acc[fr][fc] = __builtin_amdgcn_mfma_f32_16x16x32_bf16(ah[fr], bh, acc[fr][fc], 0, 0, 0);
        acc[fr][fc] = __builtin_amdgcn_mfma_f32_16x16x32_bf16(ah[fr], bl, acc[fr][fc], 0, 0, 0);
      }
    }
  }

#pragma unroll
  for (int fr = 0; fr < 4; ++fr) {
#pragma unroll
    for (int r = 0; r < 4; ++r) {
      const int grow = m0 + wr0 + fr * 16 + (lane >> 4) * 4 + r;
      const int ok = isin[grow];
#pragma unroll
      for (int fc = 0; fc < 4; ++fc) {
        const int gcol = n0 + wc0 + fc * 16 + (lane & 15);
        float v = acc[fr][fc][r] + bias[gcol];
        if (!ok) v = X[(size_t)grow * D + gcol];
        C[(size_t)grow * D + gcol] = v;
      }
    }
  }
}

// ---------------------------------------------------------------------------
// Kernel 3: gathered 16-neighbor attention (unchanged from R7).
// ---------------------------------------------------------------------------
__global__ __launch_bounds__(256) void attn_kernel(const ushort* __restrict__ qb,
                                                   const ushort* __restrict__ kb,
                                                   const ushort* __restrict__ vb,
                                                   const int* __restrict__ nbr,
                                                   ushort* __restrict__ ctx) {
  __shared__ float sc[4][NH][KN];
  const int wave = threadIdx.x >> 6;
  const int lane = threadIdx.x & 63;
  const int bl = blockIdx.x * 4 + wave;
  const int bbase = (bl >> 12) << 12;
  const int* nb = nbr + (size_t)bl * KN;

  const int h = lane >> 3;
  const int n0 = lane & 7;

  const ushort* qp = qb + (size_t)bl * D + h * DH;
  uint4 qv[8];
#pragma unroll
  for (int i = 0; i < 8; ++i)
    qv[i] = *reinterpret_cast<const uint4*>(qp + i * 8);

#pragma unroll
  for (int t = 0; t < 2; ++t) {
    const int j = nb[n0 + t * 8];
    const ushort* kr = kb + (size_t)(bbase + j) * D + h * DH;
    float a = 0.f;
#pragma unroll
    for (int i = 0; i < 8; ++i)
      a = dot8(qv[i], *reinterpret_cast<const uint4*>(kr + i * 8), a);
    sc[wave][h][n0 + t * 8] = a;
  }
  __syncthreads();

  float e[KN];
  float mx = -FLT_MAX;
#pragma unroll
  for (int n = 0; n < KN; ++n) mx = fmaxf(mx, sc[wave][h][n]);
  float sum = 0.f;
#pragma unroll
  for (int n = 0; n < KN; ++n) { e[n] = expf(sc[wave][h][n] - mx); sum += e[n]; }
  const float inv = 1.0f / sum;

  const int d0 = (lane & 7) * 8;
  float acc[8];
#pragma unroll
  for (int i = 0; i < 8; ++i) acc[i] = 0.f;
#pragma unroll
  for (int n = 0; n < KN; ++n) {
    const int j = nb[n];
    const uint4 vv = *reinterpret_cast<const uint4*>(
        vb + (size_t)(bbase + j) * D + h * DH + d0);
    const float w = e[n] * inv;
    acc[0] = fmaf(w, bf2f((ushort)vv.x), acc[0]);
    acc[1] = fmaf(w, bf2f((ushort)(vv.x >> 16)), acc[1]);
    acc[2] = fmaf(w, bf2f((ushort)vv.y), acc[2]);
    acc[3] = fmaf(w, bf2f((ushort)(vv.y >> 16)), acc[3]);
    acc[4] = fmaf(w, bf2f((ushort)vv.z), acc[4]);
    acc[5] = fmaf(w, bf2f((ushort)(vv.z >> 16)), acc[5]);
    acc[6] = fmaf(w, bf2f((ushort)vv.w), acc[6]);
    acc[7] = fmaf(w, bf2f((ushort)(vv.w >> 16)), acc[7]);
  }
  uint4 o;
  o.x = (unsigned)f2bf(acc[0]) | ((unsigned)f2bf(acc[1]) << 16);
  o.y = (unsigned)f2bf(acc[2]) | ((unsigned)f2bf(acc[3]) << 16);
  o.z = (unsigned)f2bf(acc[4]) | ((unsigned)f2bf(acc[5]) << 16);
  o.w = (unsigned)f2bf(acc[6]) | ((unsigned)f2bf(acc[7]) << 16);
  *reinterpret_cast<uint4*>(ctx + (size_t)bl * D + h * DH + d0) = o;
}

// ---------------------------------------------------------------------------
extern "C" void kernel_launch(void* const* d_in, const int* in_sizes, int n_in,
                              void* d_out, int out_size, void* d_ws, size_t ws_size,
                              hipStream_t stream) {
  const float* x     = (const float*)d_in[0];
  const float* pos   = (const float*)d_in[1];
  const float* in_w  = (const float*)d_in[2];
  const float* in_b  = (const float*)d_in[3];
  const float* out_w = (const float*)d_in[4];
  const float* out_b = (const float*)d_in[5];
  float* out = (float*)d_out;

  const size_t nbr_bytes  = (size_t)M * KN * sizeof(int);       // 1 MB
  const size_t isin_bytes = (size_t)M * sizeof(int);            // 64 KB
  const size_t half_bytes = (size_t)M * D * sizeof(ushort);     // 16.8 MB
  const size_t iwh_bytes  = (size_t)N_IN * D * sizeof(ushort);  // 1.5 MB
  const size_t ow_bytes   = (size_t)D * D * sizeof(ushort);     // 0.5 MB
  const size_t need = nbr_bytes + isin_bytes + 5 * half_bytes +
                      iwh_bytes + 2 * ow_bytes + 8192;
  if (ws_size < need) return;

  char* w = (char*)d_ws;
  int*    nbr  = (int*)w;    w += (nbr_bytes + 255) & ~(size_t)255;
  int*    isin = (int*)w;    w += (isin_bytes + 255) & ~(size_t)255;
  ushort* xb   = (ushort*)w; w += (half_bytes + 255) & ~(size_t)255;
  ushort* qb   = (ushort*)w; w += (half_bytes + 255) & ~(size_t)255;
  ushort* kb   = (ushort*)w; w += (half_bytes + 255) & ~(size_t)255;
  ushort* vb   = (ushort*)w; w += (half_bytes + 255) & ~(size_t)255;
  ushort* ctxb = (ushort*)w; w += (half_bytes + 255) & ~(size_t)255;
  ushort* iwh  = (ushort*)w; w += (iwh_bytes + 255) & ~(size_t)255;
  ushort* owh  = (ushort*)w; w += (ow_bytes + 255) & ~(size_t)255;
  ushort* owl  = (ushort*)w;

  // 0) one-shot fp32 -> bf16 conversions (memory-bound)
  cvt_x_kernel<<<2048, 256, 0, stream>>>(x, xb);
  cvt_w_kernel<<<512, 256, 0, stream>>>(in_w, out_w, iwh, owh, owl);

  // 1) top-k neighbors
  topk_kernel<<<B * (L / 8), 512, 0, stream>>>(pos, nbr, isin);

  // 2) in_proj (pure bf16) -> bf16 Q(scaled)/K/V
  gemm_in<<<dim3(M / BM, N_IN / BN), 256, 0, stream>>>(xb, iwh, in_b, qb, kb, vb);

  // 3) gathered neighbor attention -> bf16 ctx
  attn_kernel<<<M / 4, 256, 0, stream>>>(qb, kb, vb, nbr, ctxb);

  // 4) out_proj (bf16 A, pre-split W hi/lo) + isin select
  gemm_out<<<dim3(M / BM, D / BN), 256, 0, stream>>>(ctxb, owh, owl, out_b, out, x, isin);
}

// Round 9
// 179.357 us; speedup vs baseline: 8.8426x; 1.0650x over previous
//
#include <hip/hip_runtime.h>
#include <cfloat>
#include <cmath>

constexpr int B = 4;
constexpr int L = 4096;
constexpr int D = 512;
constexpr int NH = 8;
constexpr int DH = 64;
constexpr int KN = 16;
constexpr int M = B * L;          // 16384 rows
constexpr int N_IN = 3 * D;       // 1536

typedef __attribute__((ext_vector_type(8))) short short8;   // 8 bf16 = 4 VGPR
typedef __attribute__((ext_vector_type(4))) float f32x4;    // MFMA acc
typedef unsigned short ushort;

__device__ __forceinline__ ushort f2bf(float f) {   // RN-even bf16
  unsigned u = __float_as_uint(f);
  u = u + 0x7fffu + ((u >> 16) & 1u);
  return (ushort)(u >> 16);
}
__device__ __forceinline__ float bf2f(ushort h) {
  return __uint_as_float(((unsigned)h) << 16);
}
__device__ __forceinline__ float dot8(const uint4 qu, const uint4 ku, float a) {
  a = fmaf(bf2f((ushort)qu.x), bf2f((ushort)ku.x), a);
  a = fmaf(bf2f((ushort)(qu.x >> 16)), bf2f((ushort)(ku.x >> 16)), a);
  a = fmaf(bf2f((ushort)qu.y), bf2f((ushort)ku.y), a);
  a = fmaf(bf2f((ushort)(qu.y >> 16)), bf2f((ushort)(ku.y >> 16)), a);
  a = fmaf(bf2f((ushort)qu.z), bf2f((ushort)ku.z), a);
  a = fmaf(bf2f((ushort)(qu.z >> 16)), bf2f((ushort)(ku.z >> 16)), a);
  a = fmaf(bf2f((ushort)qu.w), bf2f((ushort)ku.w), a);
  a = fmaf(bf2f((ushort)(qu.w >> 16)), bf2f((ushort)(ku.w >> 16)), a);
  return a;
}
__device__ __forceinline__ uint2 pack4hi(const float4 v) {
  uint2 o;
  o.x = (unsigned)f2bf(v.x) | ((unsigned)f2bf(v.y) << 16);
  o.y = (unsigned)f2bf(v.z) | ((unsigned)f2bf(v.w) << 16);
  return o;
}
// async global->LDS, 16B/lane, dest = wave-uniform base + lane*16
__device__ __forceinline__ void gload16(const void* g, void* l) {
  __builtin_amdgcn_global_load_lds(
      (const __attribute__((address_space(1))) void*)g,
      (__attribute__((address_space(3))) void*)l, 16, 0, 0);
}

// ---------------------------------------------------------------------------
// Kernel 0a: x (fp32) -> xb (bf16).
// ---------------------------------------------------------------------------
__global__ __launch_bounds__(256) void cvt_x_kernel(const float* __restrict__ in,
                                                    ushort* __restrict__ out) {
  const int n8 = M * D / 8;
  for (int i = blockIdx.x * 256 + threadIdx.x; i < n8; i += gridDim.x * 256) {
    const float4 v0 = reinterpret_cast<const float4*>(in)[i * 2];
    const float4 v1 = reinterpret_cast<const float4*>(in)[i * 2 + 1];
    uint4 o;
    const uint2 a = pack4hi(v0), b2 = pack4hi(v1);
    o.x = a.x; o.y = a.y; o.z = b2.x; o.w = b2.y;
    reinterpret_cast<uint4*>(out)[i] = o;
  }
}

// ---------------------------------------------------------------------------
// Kernel 0b: in_w -> iwh (bf16 hi); out_w -> owh + owl (bf16 hi/lo split).
// ---------------------------------------------------------------------------
__global__ __launch_bounds__(256) void cvt_w_kernel(const float* __restrict__ in_w,
                                                    const float* __restrict__ out_w,
                                                    ushort* __restrict__ iwh,
                                                    ushort* __restrict__ owh,
                                                    ushort* __restrict__ owl) {
  const int ni8 = N_IN * D / 8;   // 98304
  const int no8 = D * D / 8;      // 32768
  for (int i = blockIdx.x * 256 + threadIdx.x; i < ni8 + no8; i += gridDim.x * 256) {
    if (i < ni8) {
      const float4 v0 = reinterpret_cast<const float4*>(in_w)[i * 2];
      const float4 v1 = reinterpret_cast<const float4*>(in_w)[i * 2 + 1];
      uint4 o;
      const uint2 a = pack4hi(v0), b2 = pack4hi(v1);
      o.x = a.x; o.y = a.y; o.z = b2.x; o.w = b2.y;
      reinterpret_cast<uint4*>(iwh)[i] = o;
    } else {
      const int j = i - ni8;
      const float4 v0 = reinterpret_cast<const float4*>(out_w)[j * 2];
      const float4 v1 = reinterpret_cast<const float4*>(out_w)[j * 2 + 1];
      uint4 oh, ol;
      const uint2 a = pack4hi(v0), b2 = pack4hi(v1);
      oh.x = a.x; oh.y = a.y; oh.z = b2.x; oh.w = b2.y;
      const float4 r0 = make_float4(v0.x - bf2f(f2bf(v0.x)), v0.y - bf2f(f2bf(v0.y)),
                                    v0.z - bf2f(f2bf(v0.z)), v0.w - bf2f(f2bf(v0.w)));
      const float4 r1 = make_float4(v1.x - bf2f(f2bf(v1.x)), v1.y - bf2f(f2bf(v1.y)),
                                    v1.z - bf2f(f2bf(v1.z)), v1.w - bf2f(f2bf(v1.w)));
      const uint2 c = pack4hi(r0), d2 = pack4hi(r1);
      ol.x = c.x; ol.y = c.y; ol.z = d2.x; ol.w = d2.y;
      reinterpret_cast<uint4*>(owh)[j] = oh;
      reinterpret_cast<uint4*>(owl)[j] = ol;
    }
  }
}

// ---------------------------------------------------------------------------
// Kernel 1: top-16 NN (unchanged from R7).
// ---------------------------------------------------------------------------
constexpr int TP = 65;   // padded row stride (words), 65 % 32 == 1

__global__ __launch_bounds__(512) void topk_kernel(const float* __restrict__ pos,
                                                   int* __restrict__ nbr,
                                                   int* __restrict__ isin) {
  __shared__ float sxT[64 * TP], syT[64 * TP], szT[64 * TP];  // 49.9 KB
  __shared__ unsigned long long lst[8 * 64];                  // 4 KB
  const int wave = threadIdx.x >> 6;
  const int lane = threadIdx.x & 63;
  const int b = blockIdx.x >> 9;
  const int l = (blockIdx.x & 511) * 8 + wave;
  const int row = b * L + l;

  const float* p = pos + (size_t)b * L * 3;
  for (int i = threadIdx.x; i < L; i += 512) {
    const int a = (i & 63) * TP + (i >> 6);
    sxT[a] = p[3 * i + 0];
    syT[a] = p[3 * i + 1];
    szT[a] = p[3 * i + 2];
  }
  __syncthreads();

  const int qa = (l & 63) * TP + (l >> 6);
  const float qx = sxT[qa], qy = syT[qa], qz = szT[qa];

  float mA = FLT_MAX, mB2 = FLT_MAX, mC = FLT_MAX, mD2 = FLT_MAX;
  const int base = lane * TP;
  for (int j = 0; j < 64; j += 4) {
#define D2(t, acc)                                                   \
    {                                                                \
      const int a = base + j + t;                                    \
      const float dx = qx - sxT[a], dy = qy - syT[a], dz = qz - szT[a]; \
      acc = fminf(acc, fmaf(dx, dx, fmaf(dy, dy, dz * dz)));         \
    }
    D2(0, mA) D2(1, mB2) D2(2, mC) D2(3, mD2)
#undef D2
  }
  const unsigned mbits = __float_as_uint(fminf(fminf(mA, mB2), fminf(mC, mD2)));

  unsigned lo = 1, hi = 0x40400001u;
  while (lo < hi) {
    const unsigned mid = (lo + hi) >> 1;
    const int c = __popcll(__ballot(mbits < mid));
    if (c >= 16) hi = mid; else lo = mid + 1;
  }
  const unsigned P = lo + 16;

  int cnt = 0;
  unsigned long long am = __ballot(mbits < P);
  const unsigned long long below = (1ull << lane) - 1ull;
  while (am) {
    const int pl = (int)__builtin_ctzll(am);
    am &= am - 1;
    const int a = pl * TP + lane;
    const float dx = qx - sxT[a], dy = qy - syT[a], dz = qz - szT[a];
    const float d2 = fmaf(dx, dx, fmaf(dy, dy, dz * dz));
    const bool hit = __float_as_uint(d2) < P;
    const unsigned long long msk = __ballot(hit);
    if (hit) {
      const int slot = cnt + __popcll(msk & below);
      if (slot < 64) {
        const unsigned c = (unsigned)(lane * 64 + pl);
        lst[wave * 64 + slot] =
            ((unsigned long long)__float_as_uint(sqrtf(d2)) << 32) | c;
      }
    }
    cnt += __popcll(msk);
  }
  const int n = min(cnt, 64);

  const unsigned long long mine = (lane < n) ? lst[wave * 64 + lane] : ~0ull;
  int r = 0;
  for (int i = 0; i < n; ++i) r += (lst[wave * 64 + i] < mine) ? 1 : 0;

  const int idx = (int)(unsigned)(mine & 0xffffffffu);
  const bool wr = (lane < n) && (r < 16);
  if (wr) nbr[(size_t)row * KN + r] = idx;
  const unsigned long long hit2 = __ballot(wr && idx == l);
  if (lane == 0) isin[row] = hit2 ? 1 : 0;
}

// ---------------------------------------------------------------------------
// GEMM tiles: 128x128, BK=32, 4 waves (2x2 of 64x64), 16x16x32 bf16 MFMA.
// Staging via global_load_lds (16B/lane) into LINEAR LDS [128][32] — each
// wave stages 16 rows/call (lane -> row ln/4, 16B chunk ln%4), 2 rounds
// (rows +0, +64). C/D layout col=lane&15, row=(lane>>4)*4+r  [m89-verified]
// ---------------------------------------------------------------------------
constexpr int BM = 128, BN = 128, BK = 32;

// Kernel 2a: in_proj (bf16 x bf16). Epilogue -> bf16 Q(scaled)/K/V.
__global__ __launch_bounds__(256) void gemm_in(const ushort* __restrict__ A,
                                               const ushort* __restrict__ W,
                                               const float* __restrict__ bias,
                                               ushort* __restrict__ qb,
                                               ushort* __restrict__ kb,
                                               ushort* __restrict__ vb) {
  __shared__ ushort Ah[BM * BK];   // 8 KB, linear
  __shared__ ushort Bh[BN * BK];   // 8 KB, linear

  const int tid = threadIdx.x;
  const int m0 = blockIdx.x * BM;
  const int n0 = blockIdx.y * BN;

  const int wv = tid >> 6;
  const int lane = tid & 63;
  // staging map: wave wv round rr covers rows wv*16 + rr*64 .. +15
  const int sr = wv * 16 + (lane >> 2);
  const int sc = (lane & 3) * 8;
  const ushort* Asrc = A + (size_t)(m0 + sr) * D + sc;
  const ushort* Wsrc = W + (size_t)(n0 + sr) * D + sc;
  ushort* AhB0 = Ah + (wv * 16) * BK;
  ushort* AhB1 = Ah + (wv * 16 + 64) * BK;
  ushort* BhB0 = Bh + (wv * 16) * BK;
  ushort* BhB1 = Bh + (wv * 16 + 64) * BK;

  const int wr0 = (wv >> 1) * 64;
  const int wc0 = (wv & 1) * 64;
  const int fr_row = lane & 15;
  const int kof = (lane >> 4) * 8;

  f32x4 acc[4][4];
#pragma unroll
  for (int i = 0; i < 4; ++i)
#pragma unroll
    for (int j = 0; j < 4; ++j) acc[i][j] = {0.f, 0.f, 0.f, 0.f};

  for (int k0 = 0; k0 < D; k0 += BK) {
    __syncthreads();
    gload16(Asrc + k0, AhB0);
    gload16(Asrc + (size_t)64 * D + k0, AhB1);
    gload16(Wsrc + k0, BhB0);
    gload16(Wsrc + (size_t)64 * D + k0, BhB1);
    __syncthreads();

    short8 ah[4];
#pragma unroll
    for (int fr = 0; fr < 4; ++fr)
      ah[fr] = *reinterpret_cast<const short8*>(&Ah[(wr0 + fr * 16 + fr_row) * BK + kof]);
#pragma unroll
    for (int fc = 0; fc < 4; ++fc) {
      const short8 bh = *reinterpret_cast<const short8*>(&Bh[(wc0 + fc * 16 + fr_row) * BK + kof]);
#pragma unroll
      for (int fr = 0; fr < 4; ++fr)
        acc[fr][fc] = __builtin_amdgcn_mfma_f32_16x16x32_bf16(ah[fr], bh, acc[fr][fc], 0, 0, 0);
    }
  }

  const int region = n0 >> 9;             // 0=q, 1=k, 2=v
  ushort* outb = region == 0 ? qb : (region == 1 ? kb : vb);
  const float scl = region == 0 ? 0.125f : 1.0f;
  const int nloc0 = (n0 & 511) + wc0;
#pragma unroll
  for (int fr = 0; fr < 4; ++fr) {
#pragma unroll
    for (int r = 0; r < 4; ++r) {
      const int grow = m0 + wr0 + fr * 16 + (lane >> 4) * 4 + r;
#pragma unroll
      for (int fc = 0; fc < 4; ++fc) {
        const int cc = fc * 16 + (lane & 15);
        const float v = (acc[fr][fc][r] + bias[n0 + wc0 + cc]) * scl;
        outb[(size_t)grow * D + nloc0 + cc] = f2bf(v);
      }
    }
  }
}

// Kernel 2b: out_proj. A = ctx bf16; W = pre-split bf16 hi/lo (2 MFMA chains).
__global__ __launch_bounds__(256) void gemm_out(const ushort* __restrict__ A,
                                                const ushort* __restrict__ Wh,
                                                const ushort* __restrict__ Wl,
                                                const float* __restrict__ bias,
                                                float* __restrict__ C,
                                                const float* __restrict__ X,
                                                const int* __restrict__ isin) {
  __shared__ ushort Ah[BM * BK];
  __shared__ ushort Bh[BN * BK];
  __shared__ ushort Bl[BN * BK];

  const int tid = threadIdx.x;
  const int m0 = blockIdx.x * BM;
  const int n0 = blockIdx.y * BN;

  const int wv = tid >> 6;
  const int lane = tid & 63;
  const int sr = wv * 16 + (lane >> 2);
  const int sc = (lane & 3) * 8;
  const ushort* Asrc = A + (size_t)(m0 + sr) * D + sc;
  const ushort* Hsrc = Wh + (size_t)(n0 + sr) * D + sc;
  const ushort* Lsrc = Wl + (size_t)(n0 + sr) * D + sc;
  ushort* AhB0 = Ah + (wv * 16) * BK;
  ushort* AhB1 = Ah + (wv * 16 + 64) * BK;
  ushort* BhB0 = Bh + (wv * 16) * BK;
  ushort* BhB1 = Bh + (wv * 16 + 64) * BK;
  ushort* BlB0 = Bl + (wv * 16) * BK;
  ushort* BlB1 = Bl + (wv * 16 + 64) * BK;

  const int wr0 = (wv >> 1) * 64;
  const int wc0 = (wv & 1) * 64;
  const int fr_row = lane & 15;
  const int kof = (lane >> 4) * 8;

  f32x4 acc[4][4];
#pragma unroll
  for (int i = 0; i < 4; ++i)
#pragma unroll
    for (int j = 0; j < 4; ++j) acc[i][j] = {0.f, 0.f, 0.f, 0.f};

  for (int k0 = 0; k0 < D; k0 += BK) {
    __syncthreads();
    gload16(Asrc + k0, AhB0);
    gload16(Asrc + (size_t)64 * D + k0, AhB1);
    gload16(Hsrc + k0, BhB0);
    gload16(Hsrc + (size_t)64 * D + k0, BhB1);
    gload16(Lsrc + k0, BlB0);
    gload16(Lsrc + (size_t)64 * D + k0, BlB1);
    __syncthreads();

    short8 ah[4];
#pragma unroll
    for (int fr = 0; fr < 4; ++fr)
      ah[fr] = *reinterpret_cast<const short8*>(&Ah[(wr0 + fr * 16 + fr_row) * BK + kof]);
#pragma unroll
    for (int fc = 0; fc < 4; ++fc) {
      const short8 bh = *reinterpret_cast<const short8*>(&Bh[(wc0 + fc * 16 + fr_row) * BK + kof]);
      const short8 bl = *reinterpret_cast<const short8*>(&Bl[(wc0 + fc * 16 + fr_row) * BK + kof]);
#pragma unroll
      for (int fr = 0; fr < 4; ++fr) {
        acc[fr][fc] = __builtin_amdgcn_mfma_f32_16x16x32_bf16(ah[fr], bh, acc[fr][fc], 0, 0, 0);
        acc[fr][fc] = __builtin_amdgcn_mfma_f32_16x16x32_bf16(ah[fr], bl, acc[fr][fc], 0, 0, 0);
      }
    }
  }

#pragma unroll
  for (int fr = 0; fr < 4; ++fr) {
#pragma unroll
    for (int r = 0; r < 4; ++r) {
      const int grow = m0 + wr0 + fr * 16 + (lane >> 4) * 4 + r;
      const int ok = isin[grow];
#pragma unroll
      for (int fc = 0; fc < 4; ++fc) {
        const int gcol = n0 + wc0 + fc * 16 + (lane & 15);
        float v = acc[fr][fc][r] + bias[gcol];
        if (!ok) v = X[(size_t)grow * D + gcol];
        C[(size_t)grow * D + gcol] = v;
      }
    }
  }
}

// ---------------------------------------------------------------------------
// Kernel 3: gathered 16-neighbor attention, XCD-affinity swizzled:
// batch b's queries run only on XCDs {2b, 2b+1} (blockIdx round-robins
// across the 8 XCDs), so each XCD's L2 serves one batch's 8.4 MB K/V
// instead of all batches' 33.6 MB. Bijective remap; numerics unchanged.
// ---------------------------------------------------------------------------
__global__ __launch_bounds__(256) void attn_kernel(const ushort* __restrict__ qb,
                                                   const ushort* __restrict__ kb,
                                                   const ushort* __restrict__ vb,
                                                   const int* __restrict__ nbr,
                                                   ushort* __restrict__ ctx) {
  __shared__ float sc[4][NH][KN];
  const int wave = threadIdx.x >> 6;
  const int lane = threadIdx.x & 63;
  const int xcd = blockIdx.x & 7;
  const int slot = blockIdx.x >> 3;            // 0..511
  const int b = xcd >> 1;
  const int idx = ((xcd & 1) << 9) + slot;     // 0..1023 within batch
  const int bl = b * L + idx * 4 + wave;
  const int bbase = b * L;
  const int* nb = nbr + (size_t)bl * KN;

  const int h = lane >> 3;
  const int n0 = lane & 7;

  const ushort* qp = qb + (size_t)bl * D + h * DH;
  uint4 qv[8];
#pragma unroll
  for (int i = 0; i < 8; ++i)
    qv[i] = *reinterpret_cast<const uint4*>(qp + i * 8);

#pragma unroll
  for (int t = 0; t < 2; ++t) {
    const int j = nb[n0 + t * 8];
    const ushort* kr = kb + (size_t)(bbase + j) * D + h * DH;
    float a = 0.f;
#pragma unroll
    for (int i = 0; i < 8; ++i)
      a = dot8(qv[i], *reinterpret_cast<const uint4*>(kr + i * 8), a);
    sc[wave][h][n0 + t * 8] = a;
  }
  __syncthreads();

  float e[KN];
  float mx = -FLT_MAX;
#pragma unroll
  for (int n = 0; n < KN; ++n) mx = fmaxf(mx, sc[wave][h][n]);
  float sum = 0.f;
#pragma unroll
  for (int n = 0; n < KN; ++n) { e[n] = expf(sc[wave][h][n] - mx); sum += e[n]; }
  const float inv = 1.0f / sum;

  const int d0 = (lane & 7) * 8;
  float acc[8];
#pragma unroll
  for (int i = 0; i < 8; ++i) acc[i] = 0.f;
#pragma unroll
  for (int n = 0; n < KN; ++n) {
    const int j = nb[n];
    const uint4 vv = *reinterpret_cast<const uint4*>(
        vb + (size_t)(bbase + j) * D + h * DH + d0);
    const float w = e[n] * inv;
    acc[0] = fmaf(w, bf2f((ushort)vv.x), acc[0]);
    acc[1] = fmaf(w, bf2f((ushort)(vv.x >> 16)), acc[1]);
    acc[2] = fmaf(w, bf2f((ushort)vv.y), acc[2]);
    acc[3] = fmaf(w, bf2f((ushort)(vv.y >> 16)), acc[3]);
    acc[4] = fmaf(w, bf2f((ushort)vv.z), acc[4]);
    acc[5] = fmaf(w, bf2f((ushort)(vv.z >> 16)), acc[5]);
    acc[6] = fmaf(w, bf2f((ushort)vv.w), acc[6]);
    acc[7] = fmaf(w, bf2f((ushort)(vv.w >> 16)), acc[7]);
  }
  uint4 o;
  o.x = (unsigned)f2bf(acc[0]) | ((unsigned)f2bf(acc[1]) << 16);
  o.y = (unsigned)f2bf(acc[2]) | ((unsigned)f2bf(acc[3]) << 16);
  o.z = (unsigned)f2bf(acc[4]) | ((unsigned)f2bf(acc[5]) << 16);
  o.w = (unsigned)f2bf(acc[6]) | ((unsigned)f2bf(acc[7]) << 16);
  *reinterpret_cast<uint4*>(ctx + (size_t)bl * D + h * DH + d0) = o;
}

// ---------------------------------------------------------------------------
extern "C" void kernel_launch(void* const* d_in, const int* in_sizes, int n_in,
                              void* d_out, int out_size, void* d_ws, size_t ws_size,
                              hipStream_t stream) {
  const float* x     = (const float*)d_in[0];
  const float* pos   = (const float*)d_in[1];
  const float* in_w  = (const float*)d_in[2];
  const float* in_b  = (const float*)d_in[3];
  const float* out_w = (const float*)d_in[4];
  const float* out_b = (const float*)d_in[5];
  float* out = (float*)d_out;

  const size_t nbr_bytes  = (size_t)M * KN * sizeof(int);       // 1 MB
  const size_t isin_bytes = (size_t)M * sizeof(int);            // 64 KB
  const size_t half_bytes = (size_t)M * D * sizeof(ushort);     // 16.8 MB
  const size_t iwh_bytes  = (size_t)N_IN * D * sizeof(ushort);  // 1.5 MB
  const size_t ow_bytes   = (size_t)D * D * sizeof(ushort);     // 0.5 MB
  const size_t need = nbr_bytes + isin_bytes + 5 * half_bytes +
                      iwh_bytes + 2 * ow_bytes + 8192;
  if (ws_size < need) return;

  char* w = (char*)d_ws;
  int*    nbr  = (int*)w;    w += (nbr_bytes + 255) & ~(size_t)255;
  int*    isin = (int*)w;    w += (isin_bytes + 255) & ~(size_t)255;
  ushort* xb   = (ushort*)w; w += (half_bytes + 255) & ~(size_t)255;
  ushort* qb   = (ushort*)w; w += (half_bytes + 255) & ~(size_t)255;
  ushort* kb   = (ushort*)w; w += (half_bytes + 255) & ~(size_t)255;
  ushort* vb   = (ushort*)w; w += (half_bytes + 255) & ~(size_t)255;
  ushort* ctxb = (ushort*)w; w += (half_bytes + 255) & ~(size_t)255;
  ushort* iwh  = (ushort*)w; w += (iwh_bytes + 255) & ~(size_t)255;
  ushort* owh  = (ushort*)w; w += (ow_bytes + 255) & ~(size_t)255;
  ushort* owl  = (ushort*)w;

  // 0) one-shot fp32 -> bf16 conversions (memory-bound)
  cvt_x_kernel<<<2048, 256, 0, stream>>>(x, xb);
  cvt_w_kernel<<<512, 256, 0, stream>>>(in_w, out_w, iwh, owh, owl);

  // 1) top-k neighbors
  topk_kernel<<<B * (L / 8), 512, 0, stream>>>(pos, nbr, isin);

  // 2) in_proj (pure bf16, global_load_lds staging) -> bf16 Q(scaled)/K/V
  gemm_in<<<dim3(M / BM, N_IN / BN), 256, 0, stream>>>(xb, iwh, in_b, qb, kb, vb);

  // 3) gathered neighbor attention (XCD-affinity swizzled) -> bf16 ctx
  attn_kernel<<<M / 4, 256, 0, stream>>>(qb, kb, vb, nbr, ctxb);

  // 4) out_proj (bf16 A, pre-split W hi/lo, global_load_lds) + isin select
  gemm_out<<<dim3(M / BM, D / BN), 256, 0, stream>>>(ctxb, owh, owl, out_b, out, x, isin);
}